// Round 15
// baseline (240.651 us; speedup 1.0000x reference)
//
#include <hip/hip_runtime.h>

#define KK 512
#define NN 512
#define DD 16
#define MM 64
#define MRF 16
#define NRF 64

typedef __attribute__((ext_vector_type(8))) short bf16x8;
typedef __attribute__((ext_vector_type(4))) float f32x4;
typedef __attribute__((ext_vector_type(8))) unsigned short u16x8;
typedef __attribute__((ext_vector_type(4))) unsigned short u16x4;

#define MFMA16 __builtin_amdgcn_mfma_f32_16x16x32_bf16

static __device__ __forceinline__ unsigned short f2bf(float x) {
    unsigned int u = __float_as_uint(x);
    u += 0x7fffu + ((u >> 16) & 1u);
    return (unsigned short)(u >> 16);
}
static __device__ __forceinline__ float bf2f(unsigned short b) {
    return __uint_as_float((unsigned int)b << 16);
}
static __device__ __forceinline__ unsigned int pk2(float lo, float hi) {
    return (unsigned int)f2bf(lo) | ((unsigned int)f2bf(hi) << 16);
}

union frag_cast { uint4 u; bf16x8 v; };

// ---------------------------------------------------------------------------
// Kernel B: per-k G = U_RF@U_BB, GW = G@W; emit WAVE-COALESCED fragment buffer
//   GT2f[k][ks 0..3][s 0..5][lane 0..63][j 0..3]  (6144 dwords/k)
// Folds vrfb: block k converts V_RF column k -> VRFb[k][vr(64)|vi(64)] bf16.
// ---------------------------------------------------------------------------
__global__ __launch_bounds__(256) void small_kernel(
    const float* __restrict__ U_RF, const float* __restrict__ U_BB,
    const float* __restrict__ W, const float* __restrict__ V_BB,
    const float* __restrict__ V_RF,
    unsigned int* __restrict__ GT2f, unsigned short* __restrict__ VRFb)
{
    const int k = blockIdx.x, t = threadIdx.x;
    __shared__ float sUR[2][MM][17];
    __shared__ float sUB[2][MRF][DD], sW[2][DD][DD];
    __shared__ float sVB[2][NRF][17];
    __shared__ float sG[2][MM][17], sGW[2][MM][17];

    if (t < 128) {
        const int p = t >> 6, r = t & 63;
        VRFb[(size_t)k*128 + t] = f2bf(V_RF[((size_t)p*NN + k)*NRF + r]);
    }

    const float* uf = U_RF + (size_t)k*2*MM*MRF;
    for (int i = t; i < 2*MM*MRF; i += 256) sUR[i>>10][(i>>4)&63][i&15] = uf[i];
    const float* ub = U_BB + (size_t)k*2*MRF*DD;
    for (int i = t; i < 2*MRF*DD; i += 256) sUB[i>>8][(i>>4)&15][i&15] = ub[i];
    const float* ww = W + (size_t)k*2*DD*DD;
    for (int i = t; i < 2*DD*DD; i += 256) sW[i>>8][(i>>4)&15][i&15] = ww[i];
    const float* vb = V_BB + (size_t)k*2*NRF*DD;
    for (int i = t; i < 2*NRF*DD; i += 256) sVB[i>>10][(i>>4)&63][i&15] = vb[i];
    __syncthreads();

    // Phase 1: G[m][d]  (thread = (m, d-quad))
    {
        const int m = t >> 2, dq = (t & 3) * 4;
        float gr[4] = {0,0,0,0}, gi[4] = {0,0,0,0};
#pragma unroll
        for (int r = 0; r < MRF; ++r) {
            const float ur = sUR[0][m][r], ui = sUR[1][m][r];
#pragma unroll
            for (int q = 0; q < 4; ++q) {
                const float br = sUB[0][r][dq+q], bi = sUB[1][r][dq+q];
                gr[q] += ur*br - ui*bi;
                gi[q] += ur*bi + ui*br;
            }
        }
#pragma unroll
        for (int q = 0; q < 4; ++q) { sG[0][m][dq+q] = gr[q]; sG[1][m][dq+q] = gi[q]; }
    }
    __syncthreads();

    // Phase 2: GW = G @ W
    {
        const int m = t >> 2, dq = (t & 3) * 4;
        float gwr[4] = {0,0,0,0}, gwi[4] = {0,0,0,0};
#pragma unroll
        for (int dp = 0; dp < DD; ++dp) {
            const float gr = sG[0][m][dp], gi = sG[1][m][dp];
#pragma unroll
            for (int q = 0; q < 4; ++q) {
                const float wr = sW[0][dp][dq+q], wi = sW[1][dp][dq+q];
                gwr[q] += gr*wr - gi*wi;
                gwi[q] += gr*wi + gi*wr;
            }
        }
#pragma unroll
        for (int q = 0; q < 4; ++q) { sGW[0][m][dq+q] = gwr[q]; sGW[1][m][dq+q] = gwi[q]; }
    }
    __syncthreads();

    // Phase 3: pack GT2f (thread -> lane64 = t&63, ks = t>>6)
    {
        const int lane64 = t & 63, ks = t >> 6;
        const int c = lane64 & 15, kg = lane64 >> 4;
        const int e2b = ks*16 + kg*4;
        unsigned int* dstk = GT2f + (size_t)k*6144 + ks*1536 + lane64*4;
#pragma unroll
        for (int s = 0; s < 6; ++s) {
            uint4 o;
#pragma unroll
            for (int j = 0; j < 4; ++j) {
                const int e2 = e2b + j;
                const int sl0 = 2*e2;
                const int m0 = sl0 & 63, hi = sl0 >> 6;
                const int m1 = m0 + 1;
                float v0, v1;
                if (s == 0)      { v0 = hi ? sG[1][m0][c]   : sG[0][m0][c];
                                   v1 = hi ? sG[1][m1][c]   : sG[0][m1][c]; }
                else if (s == 1) { v0 = hi ? -sG[0][m0][c]  : sG[1][m0][c];
                                   v1 = hi ? -sG[0][m1][c]  : sG[1][m1][c]; }
                else if (s == 2) { v0 = hi ? sGW[1][m0][c]  : sGW[0][m0][c];
                                   v1 = hi ? sGW[1][m1][c]  : sGW[0][m1][c]; }
                else if (s == 3) { v0 = hi ? -sGW[0][m0][c] : sGW[1][m0][c];
                                   v1 = hi ? -sGW[0][m1][c] : sGW[1][m1][c]; }
                else if (s == 4) { v0 = hi ? -sVB[1][m0][c] : sVB[0][m0][c];
                                   v1 = hi ? -sVB[1][m1][c] : sVB[0][m1][c]; }
                else             { v0 = hi ? sVB[0][m0][c]  : sVB[1][m0][c];
                                   v1 = hi ? sVB[0][m1][c]  : sVB[1][m1][c]; }
                ((unsigned int*)&o)[j] = pk2(v0, v1);
            }
            *reinterpret_cast<uint4*>(dstk + s*256) = o;
        }
    }
}

// ---------------------------------------------------------------------------
// Kernel C: prep_main (r14 config, at structural floor ~78us — unchanged).
// ---------------------------------------------------------------------------
__global__ __launch_bounds__(512, 8) void prep_main(
    const float* __restrict__ H, const unsigned int* __restrict__ GT2f,
    const unsigned short* __restrict__ VRFb,
    const float* __restrict__ Y, const float* __restrict__ rhoX,
    unsigned short* __restrict__ tempb, unsigned short* __restrict__ TWb,
    unsigned short* __restrict__ Bb)
{
    const int nb = blockIdx.x & 3;
    const int k  = blockIdx.x >> 2;
    const int t  = threadIdx.x;
    const int n0 = nb*128;

    __shared__ unsigned int sH[64][132];   // 33.8 KB  [e2][ncol]

    const float* Hk = H + (size_t)k*128*NN + n0;
#pragma unroll
    for (int pass = 0; pass < 4; ++pass) {
        const int e2 = pass*16 + (t >> 5);
        const int c4 = (t & 31) * 4;
        const float4 a = *reinterpret_cast<const float4*>(Hk + (size_t)(2*e2  )*NN + c4);
        const float4 b = *reinterpret_cast<const float4*>(Hk + (size_t)(2*e2+1)*NN + c4);
        uint4 d;
        d.x = pk2(a.x, b.x); d.y = pk2(a.y, b.y);
        d.z = pk2(a.z, b.z); d.w = pk2(a.w, b.w);
        *reinterpret_cast<uint4*>(&sH[e2][c4]) = d;
    }

    const int w = t >> 6, lane = t & 63;
    const int c = lane & 15, kg = lane >> 4;
    const float irx = 1.f / rhoX[0];
    const int ncol = w*16 + c;
    const int n = n0 + ncol;

    const size_t o0 = ((size_t)(k*2 + 0)*NN + n)*DD + kg*4;
    const size_t o1 = ((size_t)(k*2 + 1)*NN + n)*DD + kg*4;
    const float4 y0 = *reinterpret_cast<const float4*>(Y + o0);
    const float4 y1 = *reinterpret_cast<const float4*>(Y + o1);

    __syncthreads();

    f32x4 aTr = (f32x4)0.f, aTi = (f32x4)0.f;
    f32x4 aWr = (f32x4)0.f, aWi = (f32x4)0.f;
    f32x4 aVr = (f32x4)0.f, aVi = (f32x4)0.f;

    const unsigned int* gk = GT2f + (size_t)k*6144 + lane*4;

#pragma unroll
    for (int ks = 0; ks < 4; ++ks) {
        const int slot0 = ks*32 + kg*8;
        const int e2b = ks*16 + kg*4;
        frag_cast fh, g0, g1, g2, g3, v0, v1;
        fh.u.x = sH[e2b+0][ncol];
        fh.u.y = sH[e2b+1][ncol];
        fh.u.z = sH[e2b+2][ncol];
        fh.u.w = sH[e2b+3][ncol];
        const unsigned int* gb = gk + ks*1536;
        g0.u = *reinterpret_cast<const uint4*>(gb);
        g1.u = *reinterpret_cast<const uint4*>(gb + 256);
        g2.u = *reinterpret_cast<const uint4*>(gb + 512);
        g3.u = *reinterpret_cast<const uint4*>(gb + 768);
        v0.u = *reinterpret_cast<const uint4*>(gb + 1024);
        v1.u = *reinterpret_cast<const uint4*>(gb + 1280);
        const bf16x8 bv = *reinterpret_cast<const bf16x8*>(VRFb + (size_t)n*128 + slot0);

        aTr = MFMA16(g0.v, fh.v, aTr, 0, 0, 0);
        aTi = MFMA16(g1.v, fh.v, aTi, 0, 0, 0);
        aWr = MFMA16(g2.v, fh.v, aWr, 0, 0, 0);
        aWi = MFMA16(g3.v, fh.v, aWi, 0, 0, 0);
        aVr = MFMA16(v0.v, bv, aVr, 0, 0, 0);
        aVi = MFMA16(v1.v, bv, aVi, 0, 0, 0);
    }

    {
        const float y0a[4] = {y0.x, y0.y, y0.z, y0.w};
        const float y1a[4] = {y1.x, y1.y, y1.z, y1.w};
        u16x4 tr_, ti_, wr_, wi_, br_, bi_;
#pragma unroll
        for (int r = 0; r < 4; ++r) {
            tr_[r] = f2bf(aTr[r]);  ti_[r] = f2bf(aTi[r]);
            wr_[r] = f2bf(aWr[r]);  wi_[r] = f2bf(aWi[r]);
            br_[r] = f2bf(aWr[r] + 0.5f*(aVr[r]*irx - y0a[r]));
            bi_[r] = f2bf(aWi[r] + 0.5f*(aVi[r]*irx - y1a[r]));
        }
        *reinterpret_cast<u16x4*>(tempb + o0) = tr_;
        *reinterpret_cast<u16x4*>(tempb + o1) = ti_;
        *reinterpret_cast<u16x4*>(TWb + o0)   = wr_;
        *reinterpret_cast<u16x4*>(TWb + o1)   = wi_;
        *reinterpret_cast<u16x4*>(Bb + o0)    = br_;
        *reinterpret_cast<u16x4*>(Bb + o1)    = bi_;
    }
}

// ---------------------------------------------------------------------------
// Kernel D: Epart[ks] = sum_{kappa slice} TW @ temp^H. Split-K 16 (was 8):
// grid (8*16, 8) = 1024 blocks -> 4 blocks/CU (2x waves/SIMD for latency
// hiding; egemm was 25%-occupancy latency-bound).
// ---------------------------------------------------------------------------
__global__ __launch_bounds__(256) void egemm_kernel(
    const unsigned short* __restrict__ TWb, const unsigned short* __restrict__ tmpb,
    float* __restrict__ Epart)
{
    const int ib = blockIdx.x >> 4;
    const int ks = blockIdx.x & 15;
    const int jb = blockIdx.y;
    const int w    = threadIdx.x >> 6;
    const int lane = threadIdx.x & 63;
    const int m  = lane & 15;
    const int kg = lane >> 4;
    const int iw = ib*64 + (w>>1)*32;
    const int jw = jb*64 + (w&1)*32;
    const int d0  = (kg & 1) * 8;
    const int kof = kg >> 1;

    f32x4 RR[2][2], II[2][2], RI[2][2], IR[2][2];
#pragma unroll
    for (int is = 0; is < 2; ++is)
#pragma unroll
        for (int js = 0; js < 2; ++js) {
            RR[is][js] = (f32x4)0.f; II[is][js] = (f32x4)0.f;
            RI[is][js] = (f32x4)0.f; IR[is][js] = (f32x4)0.f;
        }

#pragma unroll 4
    for (int c = 0; c < 16; ++c) {
        const int chunk = ks*16 + c;
        const int kp = chunk*2 + kof;
        const unsigned short* Ab = TWb  + ((size_t)(kp*2+0)*NN + iw + m)*DD + d0;
        const unsigned short* Bb2 = tmpb + ((size_t)(kp*2+0)*NN + jw + m)*DD + d0;
        bf16x8 ar[2], ai[2], br[2], bi[2];
#pragma unroll
        for (int is = 0; is < 2; ++is) {
            ar[is] = *reinterpret_cast<const bf16x8*>(Ab + (size_t)is*16*DD);
            ai[is] = *reinterpret_cast<const bf16x8*>(Ab + (size_t)NN*DD + (size_t)is*16*DD);
        }
#pragma unroll
        for (int js = 0; js < 2; ++js) {
            br[js] = *reinterpret_cast<const bf16x8*>(Bb2 + (size_t)js*16*DD);
            bi[js] = *reinterpret_cast<const bf16x8*>(Bb2 + (size_t)NN*DD + (size_t)js*16*DD);
        }
#pragma unroll
        for (int is = 0; is < 2; ++is)
#pragma unroll
            for (int js = 0; js < 2; ++js) {
                RR[is][js] = MFMA16(ar[is], br[js], RR[is][js], 0, 0, 0);
                II[is][js] = MFMA16(ai[is], bi[js], II[is][js], 0, 0, 0);
                RI[is][js] = MFMA16(ar[is], bi[js], RI[is][js], 0, 0, 0);
                IR[is][js] = MFMA16(ai[is], br[js], IR[is][js], 0, 0, 0);
            }
    }

    float* Eb = Epart + (size_t)ks*2*NN*NN;
#pragma unroll
    for (int is = 0; is < 2; ++is)
#pragma unroll
        for (int js = 0; js < 2; ++js) {
            const int i = iw + is*16 + kg*4;
            const int jx = jw + js*16 + m;
#pragma unroll
            for (int r = 0; r < 4; ++r) {
                Eb[(size_t)(i+r)*NN + jx]               = RR[is][js][r] + II[is][js][r];
                Eb[(size_t)NN*NN + (size_t)(i+r)*NN + jx] = IR[is][js][r] - RI[is][js][r];
            }
        }
}

// ---------------------------------------------------------------------------
// Kernel E: M = (sum of 16 Epart)/c ; P = -M ; T1 = I + P  (bf16 + transposes)
// ---------------------------------------------------------------------------
__global__ __launch_bounds__(256) void reduceinit_kernel(
    const float* __restrict__ Epart,
    const float* __restrict__ rhoX, const float* __restrict__ mu,
    unsigned short* __restrict__ P, unsigned short* __restrict__ PT,
    unsigned short* __restrict__ T1, unsigned short* __restrict__ T1T)
{
    const size_t idx = (size_t)blockIdx.x*256 + threadIdx.x;   // over 2*NN*NN
    const float ic = 1.f / (1.f/(2.f*rhoX[0]) + mu[0]);
    const size_t pl = (size_t)2*NN*NN;
    float s = 0.f;
#pragma unroll
    for (int ks = 0; ks < 16; ++ks) s += Epart[(size_t)ks*pl + idx];
    const float mm = s * ic;
    const int p = (int)(idx / ((size_t)NN*NN));
    const size_t rem = idx - (size_t)p*NN*NN;
    const int i = (int)(rem / NN), jx = (int)(rem % NN);
    const unsigned short pv = f2bf(-mm);
    const unsigned short tv = f2bf(((p == 0 && i == jx) ? 1.f : 0.f) - mm);
    const size_t tidx = (size_t)p*NN*NN + (size_t)jx*NN + i;
    P[idx] = pv;  PT[tidx] = pv;
    T1[idx] = tv; T1T[tidx] = tv;
}

// ---------------------------------------------------------------------------
// Kernel F: D = A@B (+B)  (complex MFMA; optional D^T via LDS-staged
// coalesced transpose). unroll 8 widens the scheduler's load window.
// ---------------------------------------------------------------------------
template<bool ADD_B, bool WRITE_T>
__global__ __launch_bounds__(256) void mm_kernel(
    const unsigned short* __restrict__ A, const unsigned short* __restrict__ BT,
    unsigned short* __restrict__ D, unsigned short* __restrict__ DT)
{
    const int w    = threadIdx.x >> 6;
    const int lane = threadIdx.x & 63;
    const int m  = lane & 15;
    const int kg = lane >> 4;
    const int i0 = blockIdx.y*32;
    const int j0 = blockIdx.x*32;
    const int iw = (w>>1)*16;
    const int jw = (w&1)*16;

    __shared__ unsigned short sD[2][32][34];

    f32x4 RR = (f32x4)0.f, II = (f32x4)0.f, RI = (f32x4)0.f, IR = (f32x4)0.f;

#pragma unroll 8
    for (int c = 0; c < 16; ++c) {
        const int l0 = c*32 + kg*8;
        const bf16x8 ar = *reinterpret_cast<const bf16x8*>(A  + (size_t)(i0+iw+m)*NN + l0);
        const bf16x8 ai = *reinterpret_cast<const bf16x8*>(A  + (size_t)NN*NN + (size_t)(i0+iw+m)*NN + l0);
        const bf16x8 br = *reinterpret_cast<const bf16x8*>(BT + (size_t)(j0+jw+m)*NN + l0);
        const bf16x8 bi = *reinterpret_cast<const bf16x8*>(BT + (size_t)NN*NN + (size_t)(j0+jw+m)*NN + l0);
        RR = MFMA16(ar, br, RR, 0, 0, 0);
        II = MFMA16(ai, bi, II, 0, 0, 0);
        RI = MFMA16(ar, bi, RI, 0, 0, 0);
        IR = MFMA16(ai, br, IR, 0, 0, 0);
    }
    const int i = i0 + iw + kg*4;
    const int jx = j0 + jw + m;
    float adr[4] = {0.f,0.f,0.f,0.f}, adi[4] = {0.f,0.f,0.f,0.f};
    if (ADD_B) {
        const u16x4 badr = *reinterpret_cast<const u16x4*>(BT + (size_t)jx*NN + i);
        const u16x4 badi = *reinterpret_cast<const u16x4*>(BT + (size_t)NN*NN + (size_t)jx*NN + i);
#pragma unroll
        for (int r = 0; r < 4; ++r) { adr[r] = bf2f(badr[r]); adi[r] = bf2f(badi[r]); }
    }
#pragma unroll
    for (int r = 0; r < 4; ++r) {
        const unsigned short dr_ = f2bf(RR[r] - II[r] + adr[r]);
        const unsigned short di_ = f2bf(RI[r] + IR[r] + adi[r]);
        D[(size_t)(i+r)*NN + jx] = dr_;
        D[(size_t)NN*NN + (size_t)(i+r)*NN + jx] = di_;
        if (WRITE_T) {
            sD[0][iw + kg*4 + r][jw + m] = dr_;
            sD[1][iw + kg*4 + r][jw + m] = di_;
        }
    }
    if (WRITE_T) {
        __syncthreads();
        const int t = threadIdx.x;
        const int r8 = t >> 2, seg = t & 3;       // r8 0..63, seg 0..3
        const int plane = r8 >> 5, jloc = r8 & 31;
        u16x8 v;
#pragma unroll
        for (int e = 0; e < 8; ++e) v[e] = sD[plane][seg*8 + e][jloc];
        *reinterpret_cast<u16x8*>(DT + (size_t)plane*NN*NN +
                                  (size_t)(j0 + jloc)*NN + i0 + seg*8) = v;
    }
}

// ---------------------------------------------------------------------------
// Kernel G: X[k] = (S @ B[k]) * ic + params4[k].  1 k per block (33.3 KB LDS
// -> 4 blocks/CU, 16 waves = 2x occupancy vs r14's 66.5KB 2-k version).
// ---------------------------------------------------------------------------
__global__ __launch_bounds__(256) void final_kernel(
    const unsigned short* __restrict__ Sb, const unsigned short* __restrict__ Bb,
    const float* __restrict__ par4,
    const float* __restrict__ rhoX, const float* __restrict__ mu,
    float* __restrict__ Xout)
{
    const int k = blockIdx.x;
    __shared__ __align__(16) unsigned short sBT[2][DD][520];

    {   // stage + transpose B[k] ([2][512][16] -> [2][16][512])
        const unsigned short* Bk = Bb + (size_t)k*2*NN*DD;
        for (int q = 0; q < 8; ++q) {
            const int t8 = q*256 + threadIdx.x;    // 0..2047
            const u16x8 v = *reinterpret_cast<const u16x8*>(Bk + (size_t)t8*8);
            const int flat = t8*8;
            const int p = flat >> 13, n = (flat >> 4) & 511, dd0 = flat & 15;
#pragma unroll
            for (int jj = 0; jj < 8; ++jj) sBT[p][dd0+jj][n] = v[jj];
        }
    }
    __syncthreads();

    const int w    = threadIdx.x >> 6;
    const int lane = threadIdx.x & 63;
    const int m  = lane & 15;
    const int kg = lane >> 4;
    const int i0 = blockIdx.y*64 + w*16;

    f32x4 RR = (f32x4)0.f, II = (f32x4)0.f, RI = (f32x4)0.f, IR = (f32x4)0.f;

#pragma unroll 4
    for (int c = 0; c < 16; ++c) {
        const int l0 = c*32 + kg*8;
        const bf16x8 ar = *reinterpret_cast<const bf16x8*>(Sb + (size_t)(i0+m)*NN + l0);
        const bf16x8 ai = *reinterpret_cast<const bf16x8*>(Sb + (size_t)NN*NN + (size_t)(i0+m)*NN + l0);
        const bf16x8 br = *reinterpret_cast<const bf16x8*>(&sBT[0][m][l0]);
        const bf16x8 bi = *reinterpret_cast<const bf16x8*>(&sBT[1][m][l0]);
        RR = MFMA16(ar, br, RR, 0, 0, 0);
        II = MFMA16(ai, bi, II, 0, 0, 0);
        RI = MFMA16(ar, bi, RI, 0, 0, 0);
        IR = MFMA16(ai, br, IR, 0, 0, 0);
    }
    const float ic = 1.f / (1.f/(2.f*rhoX[0]) + mu[0]);
#pragma unroll
    for (int r = 0; r < 4; ++r) {
        const int i = i0 + kg*4 + r;
        const int d = m;
        const size_t idx0 = ((size_t)(k*2+0)*NN + i)*DD + d;
        const size_t idx1 = ((size_t)(k*2+1)*NN + i)*DD + d;
        Xout[idx0] = (RR[r] - II[r])*ic + par4[idx0];
        Xout[idx1] = (RI[r] + IR[r])*ic + par4[idx1];
    }
}

// ---------------------------------------------------------------------------
extern "C" void kernel_launch(void* const* d_in, const int* in_sizes, int n_in,
                              void* d_out, int out_size, void* d_ws, size_t ws_size,
                              hipStream_t stream) {
    const float* H     = (const float*)d_in[0];
    const float* U_RF  = (const float*)d_in[1];
    const float* U_BB  = (const float*)d_in[2];
    const float* W     = (const float*)d_in[3];
    const float* V_RF  = (const float*)d_in[4];
    const float* V_BB  = (const float*)d_in[5];
    const float* Y     = (const float*)d_in[6];
    // d_in[7] = rho (unused by reference)
    const float* rhoX  = (const float*)d_in[8];
    const float* mu    = (const float*)d_in[9];
    const float* par4  = (const float*)d_in[10];
    float* Xout = (float*)d_out;

    unsigned short* u = (unsigned short*)d_ws;
    const size_t bigE = (size_t)KK*2*NN*DD;    // 8,388,608
    const size_t plE  = (size_t)2*NN*NN;       //   524,288
    unsigned short* tempb = u;
    unsigned short* TWb   = tempb + bigE;
    unsigned short* Bb    = TWb + bigE;
    unsigned int*   GT2f  = (unsigned int*)(Bb + bigE);          // 512*6144 dwords
    unsigned short* VRFb  = (unsigned short*)(GT2f + (size_t)KK*6144);  // 512*128
    unsigned short* Pm    = VRFb + (size_t)NN*128;
    unsigned short* PmT   = Pm  + plE;
    unsigned short* T1    = PmT + plE;
    unsigned short* T1T   = T1  + plE;
    unsigned short* Q     = T1T + plE;
    unsigned short* QT    = Q   + plE;
    unsigned short* R     = QT  + plE;
    unsigned short* RT    = R   + plE;
    unsigned short* T2    = RT  + plE;
    unsigned short* T2T   = T2  + plE;
    unsigned short* T3    = T2T + plE;
    unsigned short* T3T   = T3  + plE;
    unsigned short* R2    = T3T + plE;
    unsigned short* Ss    = R2  + plE;
    float* Epart = (float*)(Ss + plE);                           // 16*plE floats

    small_kernel<<<KK, 256, 0, stream>>>(U_RF, U_BB, W, V_BB, V_RF, GT2f, VRFb);
    prep_main<<<KK*4, 512, 0, stream>>>(H, GT2f, VRFb, Y, rhoX,
                                        tempb, TWb, Bb);
    egemm_kernel<<<dim3(128, 8), 256, 0, stream>>>(TWb, tempb, Epart);
    reduceinit_kernel<<<(int)(plE/256), 256, 0, stream>>>(Epart, rhoX, mu,
                                                          Pm, PmT, T1, T1T);
    // S = (I+P)(I+P^2)(I+P^4)(I+P^8), P = -M  -> Neumann degree 15
    mm_kernel<false,true ><<<dim3(16,16), 256, 0, stream>>>(Pm, PmT, Q,  QT);   // Q  = P*P
    mm_kernel<true ,true ><<<dim3(16,16), 256, 0, stream>>>(Q,  T1T, T2, T2T);  // T2 = T1 + Q*T1
    mm_kernel<false,true ><<<dim3(16,16), 256, 0, stream>>>(Q,  QT,  R,  RT);   // R  = Q*Q
    mm_kernel<true ,true ><<<dim3(16,16), 256, 0, stream>>>(R,  T2T, T3, T3T);  // T3 = T2 + R*T2
    mm_kernel<false,false><<<dim3(16,16), 256, 0, stream>>>(R,  RT,  R2, nullptr); // R2 = R*R
    mm_kernel<true ,false><<<dim3(16,16), 256, 0, stream>>>(R2, T3T, Ss, nullptr); // S = T3 + R2*T3
    final_kernel<<<dim3(KK, 8), 256, 0, stream>>>(Ss, Bb, par4, rhoX, mu, Xout);
}

// Round 16
// 211.963 us; speedup vs baseline: 1.1353x; 1.1353x over previous
//
#include <hip/hip_runtime.h>

#define KK 512
#define NN 512
#define DD 16
#define MM 64
#define MRF 16
#define NRF 64

typedef __attribute__((ext_vector_type(8))) short bf16x8;
typedef __attribute__((ext_vector_type(4))) float f32x4;
typedef __attribute__((ext_vector_type(8))) unsigned short u16x8;
typedef __attribute__((ext_vector_type(4))) unsigned short u16x4;

#define MFMA16 __builtin_amdgcn_mfma_f32_16x16x32_bf16

static __device__ __forceinline__ unsigned short f2bf(float x) {
    unsigned int u = __float_as_uint(x);
    u += 0x7fffu + ((u >> 16) & 1u);
    return (unsigned short)(u >> 16);
}
static __device__ __forceinline__ float bf2f(unsigned short b) {
    return __uint_as_float((unsigned int)b << 16);
}
static __device__ __forceinline__ unsigned int pk2(float lo, float hi) {
    return (unsigned int)f2bf(lo) | ((unsigned int)f2bf(hi) << 16);
}

union frag_cast { uint4 u; bf16x8 v; };

// ---------------------------------------------------------------------------
// Kernel B: per-k G = U_RF@U_BB, GW = G@W; emit WAVE-COALESCED fragment buffer
//   GT2f[k][ks 0..3][s 0..5][lane 0..63][j 0..3]  (6144 dwords/k)
// Folds vrfb: block k converts V_RF column k -> VRFb[k][vr(64)|vi(64)] bf16.
// ---------------------------------------------------------------------------
__global__ __launch_bounds__(256) void small_kernel(
    const float* __restrict__ U_RF, const float* __restrict__ U_BB,
    const float* __restrict__ W, const float* __restrict__ V_BB,
    const float* __restrict__ V_RF,
    unsigned int* __restrict__ GT2f, unsigned short* __restrict__ VRFb)
{
    const int k = blockIdx.x, t = threadIdx.x;
    __shared__ float sUR[2][MM][17];
    __shared__ float sUB[2][MRF][DD], sW[2][DD][DD];
    __shared__ float sVB[2][NRF][17];
    __shared__ float sG[2][MM][17], sGW[2][MM][17];

    if (t < 128) {
        const int p = t >> 6, r = t & 63;
        VRFb[(size_t)k*128 + t] = f2bf(V_RF[((size_t)p*NN + k)*NRF + r]);
    }

    const float* uf = U_RF + (size_t)k*2*MM*MRF;
    for (int i = t; i < 2*MM*MRF; i += 256) sUR[i>>10][(i>>4)&63][i&15] = uf[i];
    const float* ub = U_BB + (size_t)k*2*MRF*DD;
    for (int i = t; i < 2*MRF*DD; i += 256) sUB[i>>8][(i>>4)&15][i&15] = ub[i];
    const float* ww = W + (size_t)k*2*DD*DD;
    for (int i = t; i < 2*DD*DD; i += 256) sW[i>>8][(i>>4)&15][i&15] = ww[i];
    const float* vb = V_BB + (size_t)k*2*NRF*DD;
    for (int i = t; i < 2*NRF*DD; i += 256) sVB[i>>10][(i>>4)&63][i&15] = vb[i];
    __syncthreads();

    // Phase 1: G[m][d]  (thread = (m, d-quad))
    {
        const int m = t >> 2, dq = (t & 3) * 4;
        float gr[4] = {0,0,0,0}, gi[4] = {0,0,0,0};
#pragma unroll
        for (int r = 0; r < MRF; ++r) {
            const float ur = sUR[0][m][r], ui = sUR[1][m][r];
#pragma unroll
            for (int q = 0; q < 4; ++q) {
                const float br = sUB[0][r][dq+q], bi = sUB[1][r][dq+q];
                gr[q] += ur*br - ui*bi;
                gi[q] += ur*bi + ui*br;
            }
        }
#pragma unroll
        for (int q = 0; q < 4; ++q) { sG[0][m][dq+q] = gr[q]; sG[1][m][dq+q] = gi[q]; }
    }
    __syncthreads();

    // Phase 2: GW = G @ W
    {
        const int m = t >> 2, dq = (t & 3) * 4;
        float gwr[4] = {0,0,0,0}, gwi[4] = {0,0,0,0};
#pragma unroll
        for (int dp = 0; dp < DD; ++dp) {
            const float gr = sG[0][m][dp], gi = sG[1][m][dp];
#pragma unroll
            for (int q = 0; q < 4; ++q) {
                const float wr = sW[0][dp][dq+q], wi = sW[1][dp][dq+q];
                gwr[q] += gr*wr - gi*wi;
                gwi[q] += gr*wi + gi*wr;
            }
        }
#pragma unroll
        for (int q = 0; q < 4; ++q) { sGW[0][m][dq+q] = gwr[q]; sGW[1][m][dq+q] = gwi[q]; }
    }
    __syncthreads();

    // Phase 3: pack GT2f (thread -> lane64 = t&63, ks = t>>6)
    {
        const int lane64 = t & 63, ks = t >> 6;
        const int c = lane64 & 15, kg = lane64 >> 4;
        const int e2b = ks*16 + kg*4;
        unsigned int* dstk = GT2f + (size_t)k*6144 + ks*1536 + lane64*4;
#pragma unroll
        for (int s = 0; s < 6; ++s) {
            uint4 o;
#pragma unroll
            for (int j = 0; j < 4; ++j) {
                const int e2 = e2b + j;
                const int sl0 = 2*e2;
                const int m0 = sl0 & 63, hi = sl0 >> 6;
                const int m1 = m0 + 1;
                float v0, v1;
                if (s == 0)      { v0 = hi ? sG[1][m0][c]   : sG[0][m0][c];
                                   v1 = hi ? sG[1][m1][c]   : sG[0][m1][c]; }
                else if (s == 1) { v0 = hi ? -sG[0][m0][c]  : sG[1][m0][c];
                                   v1 = hi ? -sG[0][m1][c]  : sG[1][m1][c]; }
                else if (s == 2) { v0 = hi ? sGW[1][m0][c]  : sGW[0][m0][c];
                                   v1 = hi ? sGW[1][m1][c]  : sGW[0][m1][c]; }
                else if (s == 3) { v0 = hi ? -sGW[0][m0][c] : sGW[1][m0][c];
                                   v1 = hi ? -sGW[0][m1][c] : sGW[1][m1][c]; }
                else if (s == 4) { v0 = hi ? -sVB[1][m0][c] : sVB[0][m0][c];
                                   v1 = hi ? -sVB[1][m1][c] : sVB[0][m1][c]; }
                else             { v0 = hi ? sVB[0][m0][c]  : sVB[1][m0][c];
                                   v1 = hi ? sVB[0][m1][c]  : sVB[1][m1][c]; }
                ((unsigned int*)&o)[j] = pk2(v0, v1);
            }
            *reinterpret_cast<uint4*>(dstk + s*256) = o;
        }
    }
}

// ---------------------------------------------------------------------------
// Kernel C: prep_main (r14 config, at structural floor ~78us — unchanged).
// ---------------------------------------------------------------------------
__global__ __launch_bounds__(512, 8) void prep_main(
    const float* __restrict__ H, const unsigned int* __restrict__ GT2f,
    const unsigned short* __restrict__ VRFb,
    const float* __restrict__ Y, const float* __restrict__ rhoX,
    unsigned short* __restrict__ tempb, unsigned short* __restrict__ TWb,
    unsigned short* __restrict__ Bb)
{
    const int nb = blockIdx.x & 3;
    const int k  = blockIdx.x >> 2;
    const int t  = threadIdx.x;
    const int n0 = nb*128;

    __shared__ unsigned int sH[64][132];   // 33.8 KB  [e2][ncol]

    const float* Hk = H + (size_t)k*128*NN + n0;
#pragma unroll
    for (int pass = 0; pass < 4; ++pass) {
        const int e2 = pass*16 + (t >> 5);
        const int c4 = (t & 31) * 4;
        const float4 a = *reinterpret_cast<const float4*>(Hk + (size_t)(2*e2  )*NN + c4);
        const float4 b = *reinterpret_cast<const float4*>(Hk + (size_t)(2*e2+1)*NN + c4);
        uint4 d;
        d.x = pk2(a.x, b.x); d.y = pk2(a.y, b.y);
        d.z = pk2(a.z, b.z); d.w = pk2(a.w, b.w);
        *reinterpret_cast<uint4*>(&sH[e2][c4]) = d;
    }

    const int w = t >> 6, lane = t & 63;
    const int c = lane & 15, kg = lane >> 4;
    const float irx = 1.f / rhoX[0];
    const int ncol = w*16 + c;
    const int n = n0 + ncol;

    const size_t o0 = ((size_t)(k*2 + 0)*NN + n)*DD + kg*4;
    const size_t o1 = ((size_t)(k*2 + 1)*NN + n)*DD + kg*4;
    const float4 y0 = *reinterpret_cast<const float4*>(Y + o0);
    const float4 y1 = *reinterpret_cast<const float4*>(Y + o1);

    __syncthreads();

    f32x4 aTr = (f32x4)0.f, aTi = (f32x4)0.f;
    f32x4 aWr = (f32x4)0.f, aWi = (f32x4)0.f;
    f32x4 aVr = (f32x4)0.f, aVi = (f32x4)0.f;

    const unsigned int* gk = GT2f + (size_t)k*6144 + lane*4;

#pragma unroll
    for (int ks = 0; ks < 4; ++ks) {
        const int slot0 = ks*32 + kg*8;
        const int e2b = ks*16 + kg*4;
        frag_cast fh, g0, g1, g2, g3, v0, v1;
        fh.u.x = sH[e2b+0][ncol];
        fh.u.y = sH[e2b+1][ncol];
        fh.u.z = sH[e2b+2][ncol];
        fh.u.w = sH[e2b+3][ncol];
        const unsigned int* gb = gk + ks*1536;
        g0.u = *reinterpret_cast<const uint4*>(gb);
        g1.u = *reinterpret_cast<const uint4*>(gb + 256);
        g2.u = *reinterpret_cast<const uint4*>(gb + 512);
        g3.u = *reinterpret_cast<const uint4*>(gb + 768);
        v0.u = *reinterpret_cast<const uint4*>(gb + 1024);
        v1.u = *reinterpret_cast<const uint4*>(gb + 1280);
        const bf16x8 bv = *reinterpret_cast<const bf16x8*>(VRFb + (size_t)n*128 + slot0);

        aTr = MFMA16(g0.v, fh.v, aTr, 0, 0, 0);
        aTi = MFMA16(g1.v, fh.v, aTi, 0, 0, 0);
        aWr = MFMA16(g2.v, fh.v, aWr, 0, 0, 0);
        aWi = MFMA16(g3.v, fh.v, aWi, 0, 0, 0);
        aVr = MFMA16(v0.v, bv, aVr, 0, 0, 0);
        aVi = MFMA16(v1.v, bv, aVi, 0, 0, 0);
    }

    {
        const float y0a[4] = {y0.x, y0.y, y0.z, y0.w};
        const float y1a[4] = {y1.x, y1.y, y1.z, y1.w};
        u16x4 tr_, ti_, wr_, wi_, br_, bi_;
#pragma unroll
        for (int r = 0; r < 4; ++r) {
            tr_[r] = f2bf(aTr[r]);  ti_[r] = f2bf(aTi[r]);
            wr_[r] = f2bf(aWr[r]);  wi_[r] = f2bf(aWi[r]);
            br_[r] = f2bf(aWr[r] + 0.5f*(aVr[r]*irx - y0a[r]));
            bi_[r] = f2bf(aWi[r] + 0.5f*(aVi[r]*irx - y1a[r]));
        }
        *reinterpret_cast<u16x4*>(tempb + o0) = tr_;
        *reinterpret_cast<u16x4*>(tempb + o1) = ti_;
        *reinterpret_cast<u16x4*>(TWb + o0)   = wr_;
        *reinterpret_cast<u16x4*>(TWb + o1)   = wi_;
        *reinterpret_cast<u16x4*>(Bb + o0)    = br_;
        *reinterpret_cast<u16x4*>(Bb + o1)    = bi_;
    }
}

// ---------------------------------------------------------------------------
// Kernel D: Epart[ks] = sum_{kappa slice} TW @ temp^H  (r14 split-8 config)
// ---------------------------------------------------------------------------
__global__ __launch_bounds__(256) void egemm_kernel(
    const unsigned short* __restrict__ TWb, const unsigned short* __restrict__ tmpb,
    float* __restrict__ Epart)
{
    const int ib = blockIdx.x >> 3;
    const int ks = blockIdx.x & 7;
    const int jb = blockIdx.y;
    const int w    = threadIdx.x >> 6;
    const int lane = threadIdx.x & 63;
    const int m  = lane & 15;
    const int kg = lane >> 4;
    const int iw = ib*64 + (w>>1)*32;
    const int jw = jb*64 + (w&1)*32;
    const int d0  = (kg & 1) * 8;
    const int kof = kg >> 1;

    f32x4 RR[2][2], II[2][2], RI[2][2], IR[2][2];
#pragma unroll
    for (int is = 0; is < 2; ++is)
#pragma unroll
        for (int js = 0; js < 2; ++js) {
            RR[is][js] = (f32x4)0.f; II[is][js] = (f32x4)0.f;
            RI[is][js] = (f32x4)0.f; IR[is][js] = (f32x4)0.f;
        }

#pragma unroll 4
    for (int c = 0; c < 32; ++c) {
        const int chunk = ks*32 + c;
        const int kp = chunk*2 + kof;
        const unsigned short* Ab = TWb  + ((size_t)(kp*2+0)*NN + iw + m)*DD + d0;
        const unsigned short* Bb2 = tmpb + ((size_t)(kp*2+0)*NN + jw + m)*DD + d0;
        bf16x8 ar[2], ai[2], br[2], bi[2];
#pragma unroll
        for (int is = 0; is < 2; ++is) {
            ar[is] = *reinterpret_cast<const bf16x8*>(Ab + (size_t)is*16*DD);
            ai[is] = *reinterpret_cast<const bf16x8*>(Ab + (size_t)NN*DD + (size_t)is*16*DD);
        }
#pragma unroll
        for (int js = 0; js < 2; ++js) {
            br[js] = *reinterpret_cast<const bf16x8*>(Bb2 + (size_t)js*16*DD);
            bi[js] = *reinterpret_cast<const bf16x8*>(Bb2 + (size_t)NN*DD + (size_t)js*16*DD);
        }
#pragma unroll
        for (int is = 0; is < 2; ++is)
#pragma unroll
            for (int js = 0; js < 2; ++js) {
                RR[is][js] = MFMA16(ar[is], br[js], RR[is][js], 0, 0, 0);
                II[is][js] = MFMA16(ai[is], bi[js], II[is][js], 0, 0, 0);
                RI[is][js] = MFMA16(ar[is], bi[js], RI[is][js], 0, 0, 0);
                IR[is][js] = MFMA16(ai[is], br[js], IR[is][js], 0, 0, 0);
            }
    }

    float* Eb = Epart + (size_t)ks*2*NN*NN;
#pragma unroll
    for (int is = 0; is < 2; ++is)
#pragma unroll
        for (int js = 0; js < 2; ++js) {
            const int i = iw + is*16 + kg*4;
            const int jx = jw + js*16 + m;
#pragma unroll
            for (int r = 0; r < 4; ++r) {
                Eb[(size_t)(i+r)*NN + jx]               = RR[is][js][r] + II[is][js][r];
                Eb[(size_t)NN*NN + (size_t)(i+r)*NN + jx] = IR[is][js][r] - RI[is][js][r];
            }
        }
}

// ---------------------------------------------------------------------------
// Kernel E: M = (sum of 8 Epart)/c ; P = -M ; T1 = I + P  (bf16 + transposes)
// ---------------------------------------------------------------------------
__global__ __launch_bounds__(256) void reduceinit_kernel(
    const float* __restrict__ Epart,
    const float* __restrict__ rhoX, const float* __restrict__ mu,
    unsigned short* __restrict__ P, unsigned short* __restrict__ PT,
    unsigned short* __restrict__ T1, unsigned short* __restrict__ T1T)
{
    const size_t idx = (size_t)blockIdx.x*256 + threadIdx.x;   // over 2*NN*NN
    const float ic = 1.f / (1.f/(2.f*rhoX[0]) + mu[0]);
    const size_t pl = (size_t)2*NN*NN;
    float s = 0.f;
#pragma unroll
    for (int ks = 0; ks < 8; ++ks) s += Epart[(size_t)ks*pl + idx];
    const float mm = s * ic;
    const int p = (int)(idx / ((size_t)NN*NN));
    const size_t rem = idx - (size_t)p*NN*NN;
    const int i = (int)(rem / NN), jx = (int)(rem % NN);
    const unsigned short pv = f2bf(-mm);
    const unsigned short tv = f2bf(((p == 0 && i == jx) ? 1.f : 0.f) - mm);
    const size_t tidx = (size_t)p*NN*NN + (size_t)jx*NN + i;
    P[idx] = pv;  PT[tidx] = pv;
    T1[idx] = tv; T1T[tidx] = tv;
}

// ---------------------------------------------------------------------------
// Kernel F: D = A@B (+B)  (complex MFMA; optional D^T via LDS-staged
// coalesced transpose). unroll 8 widens the scheduler's load window.
// ---------------------------------------------------------------------------
template<bool ADD_B, bool WRITE_T>
__global__ __launch_bounds__(256) void mm_kernel(
    const unsigned short* __restrict__ A, const unsigned short* __restrict__ BT,
    unsigned short* __restrict__ D, unsigned short* __restrict__ DT)
{
    const int w    = threadIdx.x >> 6;
    const int lane = threadIdx.x & 63;
    const int m  = lane & 15;
    const int kg = lane >> 4;
    const int i0 = blockIdx.y*32;
    const int j0 = blockIdx.x*32;
    const int iw = (w>>1)*16;
    const int jw = (w&1)*16;

    __shared__ unsigned short sD[2][32][34];

    f32x4 RR = (f32x4)0.f, II = (f32x4)0.f, RI = (f32x4)0.f, IR = (f32x4)0.f;

#pragma unroll 8
    for (int c = 0; c < 16; ++c) {
        const int l0 = c*32 + kg*8;
        const bf16x8 ar = *reinterpret_cast<const bf16x8*>(A  + (size_t)(i0+iw+m)*NN + l0);
        const bf16x8 ai = *reinterpret_cast<const bf16x8*>(A  + (size_t)NN*NN + (size_t)(i0+iw+m)*NN + l0);
        const bf16x8 br = *reinterpret_cast<const bf16x8*>(BT + (size_t)(j0+jw+m)*NN + l0);
        const bf16x8 bi = *reinterpret_cast<const bf16x8*>(BT + (size_t)NN*NN + (size_t)(j0+jw+m)*NN + l0);
        RR = MFMA16(ar, br, RR, 0, 0, 0);
        II = MFMA16(ai, bi, II, 0, 0, 0);
        RI = MFMA16(ar, bi, RI, 0, 0, 0);
        IR = MFMA16(ai, br, IR, 0, 0, 0);
    }
    const int i = i0 + iw + kg*4;
    const int jx = j0 + jw + m;
    float adr[4] = {0.f,0.f,0.f,0.f}, adi[4] = {0.f,0.f,0.f,0.f};
    if (ADD_B) {
        const u16x4 badr = *reinterpret_cast<const u16x4*>(BT + (size_t)jx*NN + i);
        const u16x4 badi = *reinterpret_cast<const u16x4*>(BT + (size_t)NN*NN + (size_t)jx*NN + i);
#pragma unroll
        for (int r = 0; r < 4; ++r) { adr[r] = bf2f(badr[r]); adi[r] = bf2f(badi[r]); }
    }
#pragma unroll
    for (int r = 0; r < 4; ++r) {
        const unsigned short dr_ = f2bf(RR[r] - II[r] + adr[r]);
        const unsigned short di_ = f2bf(RI[r] + IR[r] + adi[r]);
        D[(size_t)(i+r)*NN + jx] = dr_;
        D[(size_t)NN*NN + (size_t)(i+r)*NN + jx] = di_;
        if (WRITE_T) {
            sD[0][iw + kg*4 + r][jw + m] = dr_;
            sD[1][iw + kg*4 + r][jw + m] = di_;
        }
    }
    if (WRITE_T) {
        __syncthreads();
        const int t = threadIdx.x;
        const int r8 = t >> 2, seg = t & 3;       // r8 0..63, seg 0..3
        const int plane = r8 >> 5, jloc = r8 & 31;
        u16x8 v;
#pragma unroll
        for (int e = 0; e < 8; ++e) v[e] = sD[plane][seg*8 + e][jloc];
        *reinterpret_cast<u16x8*>(DT + (size_t)plane*NN*NN +
                                  (size_t)(j0 + jloc)*NN + i0 + seg*8) = v;
    }
}

// ---------------------------------------------------------------------------
// Kernel G: X[k] = (S @ B[k]) * ic + params4[k]  (r14 2-k version; sBT pitch
// 524: 262 dwords % 32 == 6 -> b128 B-read start banks (6m+4kg)%32 spread
// 2-per-start (was pitch 520 = 8-way overlap, 4.2M conflict cycles in r15's
// 1-k variant; same pattern existed here).
// ---------------------------------------------------------------------------
__global__ __launch_bounds__(256) void final_kernel(
    const unsigned short* __restrict__ Sb, const unsigned short* __restrict__ Bb,
    const float* __restrict__ par4,
    const float* __restrict__ rhoX, const float* __restrict__ mu,
    float* __restrict__ Xout)
{
    const int k0 = blockIdx.x * 2;
    __shared__ __align__(16) unsigned short sBT[2][2][DD][524];

#pragma unroll
    for (int kk = 0; kk < 2; ++kk) {
        const unsigned short* Bk = Bb + (size_t)(k0 + kk)*2*NN*DD;
        for (int q = 0; q < 8; ++q) {
            const int t8 = q*256 + threadIdx.x;    // 0..2047
            const u16x8 v = *reinterpret_cast<const u16x8*>(Bk + (size_t)t8*8);
            const int flat = t8*8;
            const int p = flat >> 13, n = (flat >> 4) & 511, dd0 = flat & 15;
#pragma unroll
            for (int jj = 0; jj < 8; ++jj) sBT[kk][p][dd0+jj][n] = v[jj];
        }
    }
    __syncthreads();

    const int w    = threadIdx.x >> 6;
    const int lane = threadIdx.x & 63;
    const int m  = lane & 15;
    const int kg = lane >> 4;
    const int i0 = blockIdx.y*64 + w*16;

    f32x4 RR[2], II[2], RI[2], IR[2];
#pragma unroll
    for (int kk = 0; kk < 2; ++kk) {
        RR[kk] = (f32x4)0.f; II[kk] = (f32x4)0.f;
        RI[kk] = (f32x4)0.f; IR[kk] = (f32x4)0.f;
    }

#pragma unroll 4
    for (int c = 0; c < 16; ++c) {
        const int l0 = c*32 + kg*8;
        const bf16x8 ar = *reinterpret_cast<const bf16x8*>(Sb + (size_t)(i0+m)*NN + l0);
        const bf16x8 ai = *reinterpret_cast<const bf16x8*>(Sb + (size_t)NN*NN + (size_t)(i0+m)*NN + l0);
#pragma unroll
        for (int kk = 0; kk < 2; ++kk) {
            const bf16x8 br = *reinterpret_cast<const bf16x8*>(&sBT[kk][0][m][l0]);
            const bf16x8 bi = *reinterpret_cast<const bf16x8*>(&sBT[kk][1][m][l0]);
            RR[kk] = MFMA16(ar, br, RR[kk], 0, 0, 0);
            II[kk] = MFMA16(ai, bi, II[kk], 0, 0, 0);
            RI[kk] = MFMA16(ar, bi, RI[kk], 0, 0, 0);
            IR[kk] = MFMA16(ai, br, IR[kk], 0, 0, 0);
        }
    }
    const float ic = 1.f / (1.f/(2.f*rhoX[0]) + mu[0]);
#pragma unroll
    for (int kk = 0; kk < 2; ++kk) {
        const int k = k0 + kk;
#pragma unroll
        for (int r = 0; r < 4; ++r) {
            const int i = i0 + kg*4 + r;
            const int d = m;
            const size_t idx0 = ((size_t)(k*2+0)*NN + i)*DD + d;
            const size_t idx1 = ((size_t)(k*2+1)*NN + i)*DD + d;
            Xout[idx0] = (RR[kk][r] - II[kk][r])*ic + par4[idx0];
            Xout[idx1] = (RI[kk][r] + IR[kk][r])*ic + par4[idx1];
        }
    }
}

// ---------------------------------------------------------------------------
extern "C" void kernel_launch(void* const* d_in, const int* in_sizes, int n_in,
                              void* d_out, int out_size, void* d_ws, size_t ws_size,
                              hipStream_t stream) {
    const float* H     = (const float*)d_in[0];
    const float* U_RF  = (const float*)d_in[1];
    const float* U_BB  = (const float*)d_in[2];
    const float* W     = (const float*)d_in[3];
    const float* V_RF  = (const float*)d_in[4];
    const float* V_BB  = (const float*)d_in[5];
    const float* Y     = (const float*)d_in[6];
    // d_in[7] = rho (unused by reference)
    const float* rhoX  = (const float*)d_in[8];
    const float* mu    = (const float*)d_in[9];
    const float* par4  = (const float*)d_in[10];
    float* Xout = (float*)d_out;

    unsigned short* u = (unsigned short*)d_ws;
    const size_t bigE = (size_t)KK*2*NN*DD;    // 8,388,608
    const size_t plE  = (size_t)2*NN*NN;       //   524,288
    unsigned short* tempb = u;
    unsigned short* TWb   = tempb + bigE;
    unsigned short* Bb    = TWb + bigE;
    unsigned int*   GT2f  = (unsigned int*)(Bb + bigE);          // 512*6144 dwords
    unsigned short* VRFb  = (unsigned short*)(GT2f + (size_t)KK*6144);  // 512*128
    unsigned short* Pm    = VRFb + (size_t)NN*128;
    unsigned short* PmT   = Pm  + plE;
    unsigned short* T1    = PmT + plE;
    unsigned short* T1T   = T1  + plE;
    unsigned short* Q     = T1T + plE;
    unsigned short* QT    = Q   + plE;
    unsigned short* R     = QT  + plE;
    unsigned short* RT    = R   + plE;
    unsigned short* T2    = RT  + plE;
    unsigned short* T2T   = T2  + plE;
    unsigned short* T3    = T2T + plE;
    unsigned short* T3T   = T3  + plE;
    unsigned short* R2    = T3T + plE;
    unsigned short* Ss    = R2  + plE;
    float* Epart = (float*)(Ss + plE);                           // 8*plE floats

    small_kernel<<<KK, 256, 0, stream>>>(U_RF, U_BB, W, V_BB, V_RF, GT2f, VRFb);
    prep_main<<<KK*4, 512, 0, stream>>>(H, GT2f, VRFb, Y, rhoX,
                                        tempb, TWb, Bb);
    egemm_kernel<<<dim3(64, 8), 256, 0, stream>>>(TWb, tempb, Epart);
    reduceinit_kernel<<<(int)(plE/256), 256, 0, stream>>>(Epart, rhoX, mu,
                                                          Pm, PmT, T1, T1T);
    // S = (I+P)(I+P^2)(I+P^4)(I+P^8), P = -M  -> Neumann degree 15
    mm_kernel<false,true ><<<dim3(16,16), 256, 0, stream>>>(Pm, PmT, Q,  QT);   // Q  = P*P
    mm_kernel<true ,true ><<<dim3(16,16), 256, 0, stream>>>(Q,  T1T, T2, T2T);  // T2 = T1 + Q*T1
    mm_kernel<false,true ><<<dim3(16,16), 256, 0, stream>>>(Q,  QT,  R,  RT);   // R  = Q*Q
    mm_kernel<true ,true ><<<dim3(16,16), 256, 0, stream>>>(R,  T2T, T3, T3T);  // T3 = T2 + R*T2
    mm_kernel<false,false><<<dim3(16,16), 256, 0, stream>>>(R,  RT,  R2, nullptr); // R2 = R*R
    mm_kernel<true ,false><<<dim3(16,16), 256, 0, stream>>>(R2, T3T, Ss, nullptr); // S = T3 + R2*T3
    final_kernel<<<dim3(KK/2, 8), 256, 0, stream>>>(Ss, Bb, par4, rhoX, mu, Xout);
}

// Round 17
// 193.094 us; speedup vs baseline: 1.2463x; 1.0977x over previous
//
#include <hip/hip_runtime.h>

#define KK 512
#define NN 512
#define DD 16
#define MM 64
#define MRF 16
#define NRF 64

typedef __attribute__((ext_vector_type(8))) short bf16x8;
typedef __attribute__((ext_vector_type(4))) float f32x4;
typedef __attribute__((ext_vector_type(8))) unsigned short u16x8;
typedef __attribute__((ext_vector_type(4))) unsigned short u16x4;

#define MFMA16 __builtin_amdgcn_mfma_f32_16x16x32_bf16

static __device__ __forceinline__ unsigned short f2bf(float x) {
    unsigned int u = __float_as_uint(x);
    u += 0x7fffu + ((u >> 16) & 1u);
    return (unsigned short)(u >> 16);
}
static __device__ __forceinline__ float bf2f(unsigned short b) {
    return __uint_as_float((unsigned int)b << 16);
}
static __device__ __forceinline__ unsigned int pk2(float lo, float hi) {
    return (unsigned int)f2bf(lo) | ((unsigned int)f2bf(hi) << 16);
}

union frag_cast { uint4 u; bf16x8 v; };

// ---------------------------------------------------------------------------
// Kernel B: per-k G = U_RF@U_BB, GW = G@W; emit WAVE-COALESCED fragment buffer
//   GT2f[k][ks 0..3][s 0..5][lane 0..63][j 0..3]  (6144 dwords/k)
// Folds vrfb: block k converts V_RF column k -> VRFb[k][vr(64)|vi(64)] bf16.
// ---------------------------------------------------------------------------
__global__ __launch_bounds__(256) void small_kernel(
    const float* __restrict__ U_RF, const float* __restrict__ U_BB,
    const float* __restrict__ W, const float* __restrict__ V_BB,
    const float* __restrict__ V_RF,
    unsigned int* __restrict__ GT2f, unsigned short* __restrict__ VRFb)
{
    const int k = blockIdx.x, t = threadIdx.x;
    __shared__ float sUR[2][MM][17];
    __shared__ float sUB[2][MRF][DD], sW[2][DD][DD];
    __shared__ float sVB[2][NRF][17];
    __shared__ float sG[2][MM][17], sGW[2][MM][17];

    if (t < 128) {
        const int p = t >> 6, r = t & 63;
        VRFb[(size_t)k*128 + t] = f2bf(V_RF[((size_t)p*NN + k)*NRF + r]);
    }

    const float* uf = U_RF + (size_t)k*2*MM*MRF;
    for (int i = t; i < 2*MM*MRF; i += 256) sUR[i>>10][(i>>4)&63][i&15] = uf[i];
    const float* ub = U_BB + (size_t)k*2*MRF*DD;
    for (int i = t; i < 2*MRF*DD; i += 256) sUB[i>>8][(i>>4)&15][i&15] = ub[i];
    const float* ww = W + (size_t)k*2*DD*DD;
    for (int i = t; i < 2*DD*DD; i += 256) sW[i>>8][(i>>4)&15][i&15] = ww[i];
    const float* vb = V_BB + (size_t)k*2*NRF*DD;
    for (int i = t; i < 2*NRF*DD; i += 256) sVB[i>>10][(i>>4)&63][i&15] = vb[i];
    __syncthreads();

    // Phase 1: G[m][d]  (thread = (m, d-quad))
    {
        const int m = t >> 2, dq = (t & 3) * 4;
        float gr[4] = {0,0,0,0}, gi[4] = {0,0,0,0};
#pragma unroll
        for (int r = 0; r < MRF; ++r) {
            const float ur = sUR[0][m][r], ui = sUR[1][m][r];
#pragma unroll
            for (int q = 0; q < 4; ++q) {
                const float br = sUB[0][r][dq+q], bi = sUB[1][r][dq+q];
                gr[q] += ur*br - ui*bi;
                gi[q] += ur*bi + ui*br;
            }
        }
#pragma unroll
        for (int q = 0; q < 4; ++q) { sG[0][m][dq+q] = gr[q]; sG[1][m][dq+q] = gi[q]; }
    }
    __syncthreads();

    // Phase 2: GW = G @ W
    {
        const int m = t >> 2, dq = (t & 3) * 4;
        float gwr[4] = {0,0,0,0}, gwi[4] = {0,0,0,0};
#pragma unroll
        for (int dp = 0; dp < DD; ++dp) {
            const float gr = sG[0][m][dp], gi = sG[1][m][dp];
#pragma unroll
            for (int q = 0; q < 4; ++q) {
                const float wr = sW[0][dp][dq+q], wi = sW[1][dp][dq+q];
                gwr[q] += gr*wr - gi*wi;
                gwi[q] += gr*wi + gi*wr;
            }
        }
#pragma unroll
        for (int q = 0; q < 4; ++q) { sGW[0][m][dq+q] = gwr[q]; sGW[1][m][dq+q] = gwi[q]; }
    }
    __syncthreads();

    // Phase 3: pack GT2f (thread -> lane64 = t&63, ks = t>>6)
    {
        const int lane64 = t & 63, ks = t >> 6;
        const int c = lane64 & 15, kg = lane64 >> 4;
        const int e2b = ks*16 + kg*4;
        unsigned int* dstk = GT2f + (size_t)k*6144 + ks*1536 + lane64*4;
#pragma unroll
        for (int s = 0; s < 6; ++s) {
            uint4 o;
#pragma unroll
            for (int j = 0; j < 4; ++j) {
                const int e2 = e2b + j;
                const int sl0 = 2*e2;
                const int m0 = sl0 & 63, hi = sl0 >> 6;
                const int m1 = m0 + 1;
                float v0, v1;
                if (s == 0)      { v0 = hi ? sG[1][m0][c]   : sG[0][m0][c];
                                   v1 = hi ? sG[1][m1][c]   : sG[0][m1][c]; }
                else if (s == 1) { v0 = hi ? -sG[0][m0][c]  : sG[1][m0][c];
                                   v1 = hi ? -sG[0][m1][c]  : sG[1][m1][c]; }
                else if (s == 2) { v0 = hi ? sGW[1][m0][c]  : sGW[0][m0][c];
                                   v1 = hi ? sGW[1][m1][c]  : sGW[0][m1][c]; }
                else if (s == 3) { v0 = hi ? -sGW[0][m0][c] : sGW[1][m0][c];
                                   v1 = hi ? -sGW[0][m1][c] : sGW[1][m1][c]; }
                else if (s == 4) { v0 = hi ? -sVB[1][m0][c] : sVB[0][m0][c];
                                   v1 = hi ? -sVB[1][m1][c] : sVB[0][m1][c]; }
                else             { v0 = hi ? sVB[0][m0][c]  : sVB[1][m0][c];
                                   v1 = hi ? sVB[0][m1][c]  : sVB[1][m1][c]; }
                ((unsigned int*)&o)[j] = pk2(v0, v1);
            }
            *reinterpret_cast<uint4*>(dstk + s*256) = o;
        }
    }
}

// ---------------------------------------------------------------------------
// Kernel C: prep_main (r14 config, at structural floor ~78us — unchanged).
// ---------------------------------------------------------------------------
__global__ __launch_bounds__(512, 8) void prep_main(
    const float* __restrict__ H, const unsigned int* __restrict__ GT2f,
    const unsigned short* __restrict__ VRFb,
    const float* __restrict__ Y, const float* __restrict__ rhoX,
    unsigned short* __restrict__ tempb, unsigned short* __restrict__ TWb,
    unsigned short* __restrict__ Bb)
{
    const int nb = blockIdx.x & 3;
    const int k  = blockIdx.x >> 2;
    const int t  = threadIdx.x;
    const int n0 = nb*128;

    __shared__ unsigned int sH[64][132];   // 33.8 KB  [e2][ncol]

    const float* Hk = H + (size_t)k*128*NN + n0;
#pragma unroll
    for (int pass = 0; pass < 4; ++pass) {
        const int e2 = pass*16 + (t >> 5);
        const int c4 = (t & 31) * 4;
        const float4 a = *reinterpret_cast<const float4*>(Hk + (size_t)(2*e2  )*NN + c4);
        const float4 b = *reinterpret_cast<const float4*>(Hk + (size_t)(2*e2+1)*NN + c4);
        uint4 d;
        d.x = pk2(a.x, b.x); d.y = pk2(a.y, b.y);
        d.z = pk2(a.z, b.z); d.w = pk2(a.w, b.w);
        *reinterpret_cast<uint4*>(&sH[e2][c4]) = d;
    }

    const int w = t >> 6, lane = t & 63;
    const int c = lane & 15, kg = lane >> 4;
    const float irx = 1.f / rhoX[0];
    const int ncol = w*16 + c;
    const int n = n0 + ncol;

    const size_t o0 = ((size_t)(k*2 + 0)*NN + n)*DD + kg*4;
    const size_t o1 = ((size_t)(k*2 + 1)*NN + n)*DD + kg*4;
    const float4 y0 = *reinterpret_cast<const float4*>(Y + o0);
    const float4 y1 = *reinterpret_cast<const float4*>(Y + o1);

    __syncthreads();

    f32x4 aTr = (f32x4)0.f, aTi = (f32x4)0.f;
    f32x4 aWr = (f32x4)0.f, aWi = (f32x4)0.f;
    f32x4 aVr = (f32x4)0.f, aVi = (f32x4)0.f;

    const unsigned int* gk = GT2f + (size_t)k*6144 + lane*4;

#pragma unroll
    for (int ks = 0; ks < 4; ++ks) {
        const int slot0 = ks*32 + kg*8;
        const int e2b = ks*16 + kg*4;
        frag_cast fh, g0, g1, g2, g3, v0, v1;
        fh.u.x = sH[e2b+0][ncol];
        fh.u.y = sH[e2b+1][ncol];
        fh.u.z = sH[e2b+2][ncol];
        fh.u.w = sH[e2b+3][ncol];
        const unsigned int* gb = gk + ks*1536;
        g0.u = *reinterpret_cast<const uint4*>(gb);
        g1.u = *reinterpret_cast<const uint4*>(gb + 256);
        g2.u = *reinterpret_cast<const uint4*>(gb + 512);
        g3.u = *reinterpret_cast<const uint4*>(gb + 768);
        v0.u = *reinterpret_cast<const uint4*>(gb + 1024);
        v1.u = *reinterpret_cast<const uint4*>(gb + 1280);
        const bf16x8 bv = *reinterpret_cast<const bf16x8*>(VRFb + (size_t)n*128 + slot0);

        aTr = MFMA16(g0.v, fh.v, aTr, 0, 0, 0);
        aTi = MFMA16(g1.v, fh.v, aTi, 0, 0, 0);
        aWr = MFMA16(g2.v, fh.v, aWr, 0, 0, 0);
        aWi = MFMA16(g3.v, fh.v, aWi, 0, 0, 0);
        aVr = MFMA16(v0.v, bv, aVr, 0, 0, 0);
        aVi = MFMA16(v1.v, bv, aVi, 0, 0, 0);
    }

    {
        const float y0a[4] = {y0.x, y0.y, y0.z, y0.w};
        const float y1a[4] = {y1.x, y1.y, y1.z, y1.w};
        u16x4 tr_, ti_, wr_, wi_, br_, bi_;
#pragma unroll
        for (int r = 0; r < 4; ++r) {
            tr_[r] = f2bf(aTr[r]);  ti_[r] = f2bf(aTi[r]);
            wr_[r] = f2bf(aWr[r]);  wi_[r] = f2bf(aWi[r]);
            br_[r] = f2bf(aWr[r] + 0.5f*(aVr[r]*irx - y0a[r]));
            bi_[r] = f2bf(aWi[r] + 0.5f*(aVi[r]*irx - y1a[r]));
        }
        *reinterpret_cast<u16x4*>(tempb + o0) = tr_;
        *reinterpret_cast<u16x4*>(tempb + o1) = ti_;
        *reinterpret_cast<u16x4*>(TWb + o0)   = wr_;
        *reinterpret_cast<u16x4*>(TWb + o1)   = wi_;
        *reinterpret_cast<u16x4*>(Bb + o0)    = br_;
        *reinterpret_cast<u16x4*>(Bb + o1)    = bi_;
    }
}

// ---------------------------------------------------------------------------
// Kernel D: Epart[ks] = sum_{kappa slice} TW @ temp^H  (split-8)
// ---------------------------------------------------------------------------
__global__ __launch_bounds__(256) void egemm_kernel(
    const unsigned short* __restrict__ TWb, const unsigned short* __restrict__ tmpb,
    float* __restrict__ Epart)
{
    const int ib = blockIdx.x >> 3;
    const int ks = blockIdx.x & 7;
    const int jb = blockIdx.y;
    const int w    = threadIdx.x >> 6;
    const int lane = threadIdx.x & 63;
    const int m  = lane & 15;
    const int kg = lane >> 4;
    const int iw = ib*64 + (w>>1)*32;
    const int jw = jb*64 + (w&1)*32;
    const int d0  = (kg & 1) * 8;
    const int kof = kg >> 1;

    f32x4 RR[2][2], II[2][2], RI[2][2], IR[2][2];
#pragma unroll
    for (int is = 0; is < 2; ++is)
#pragma unroll
        for (int js = 0; js < 2; ++js) {
            RR[is][js] = (f32x4)0.f; II[is][js] = (f32x4)0.f;
            RI[is][js] = (f32x4)0.f; IR[is][js] = (f32x4)0.f;
        }

#pragma unroll 4
    for (int c = 0; c < 32; ++c) {
        const int chunk = ks*32 + c;
        const int kp = chunk*2 + kof;
        const unsigned short* Ab = TWb  + ((size_t)(kp*2+0)*NN + iw + m)*DD + d0;
        const unsigned short* Bb2 = tmpb + ((size_t)(kp*2+0)*NN + jw + m)*DD + d0;
        bf16x8 ar[2], ai[2], br[2], bi[2];
#pragma unroll
        for (int is = 0; is < 2; ++is) {
            ar[is] = *reinterpret_cast<const bf16x8*>(Ab + (size_t)is*16*DD);
            ai[is] = *reinterpret_cast<const bf16x8*>(Ab + (size_t)NN*DD + (size_t)is*16*DD);
        }
#pragma unroll
        for (int js = 0; js < 2; ++js) {
            br[js] = *reinterpret_cast<const bf16x8*>(Bb2 + (size_t)js*16*DD);
            bi[js] = *reinterpret_cast<const bf16x8*>(Bb2 + (size_t)NN*DD + (size_t)js*16*DD);
        }
#pragma unroll
        for (int is = 0; is < 2; ++is)
#pragma unroll
            for (int js = 0; js < 2; ++js) {
                RR[is][js] = MFMA16(ar[is], br[js], RR[is][js], 0, 0, 0);
                II[is][js] = MFMA16(ai[is], bi[js], II[is][js], 0, 0, 0);
                RI[is][js] = MFMA16(ar[is], bi[js], RI[is][js], 0, 0, 0);
                IR[is][js] = MFMA16(ai[is], br[js], IR[is][js], 0, 0, 0);
            }
    }

    float* Eb = Epart + (size_t)ks*2*NN*NN;
#pragma unroll
    for (int is = 0; is < 2; ++is)
#pragma unroll
        for (int js = 0; js < 2; ++js) {
            const int i = iw + is*16 + kg*4;
            const int jx = jw + js*16 + m;
#pragma unroll
            for (int r = 0; r < 4; ++r) {
                Eb[(size_t)(i+r)*NN + jx]               = RR[is][js][r] + II[is][js][r];
                Eb[(size_t)NN*NN + (size_t)(i+r)*NN + jx] = IR[is][js][r] - RI[is][js][r];
            }
        }
}

// ---------------------------------------------------------------------------
// Kernel E: M = (sum of 8 Epart)/c ; P = -M ; T1 = I + P  (bf16 + transposes)
// ---------------------------------------------------------------------------
__global__ __launch_bounds__(256) void reduceinit_kernel(
    const float* __restrict__ Epart,
    const float* __restrict__ rhoX, const float* __restrict__ mu,
    unsigned short* __restrict__ P, unsigned short* __restrict__ PT,
    unsigned short* __restrict__ T1, unsigned short* __restrict__ T1T)
{
    const size_t idx = (size_t)blockIdx.x*256 + threadIdx.x;   // over 2*NN*NN
    const float ic = 1.f / (1.f/(2.f*rhoX[0]) + mu[0]);
    const size_t pl = (size_t)2*NN*NN;
    float s = 0.f;
#pragma unroll
    for (int ks = 0; ks < 8; ++ks) s += Epart[(size_t)ks*pl + idx];
    const float mm = s * ic;
    const int p = (int)(idx / ((size_t)NN*NN));
    const size_t rem = idx - (size_t)p*NN*NN;
    const int i = (int)(rem / NN), jx = (int)(rem % NN);
    const unsigned short pv = f2bf(-mm);
    const unsigned short tv = f2bf(((p == 0 && i == jx) ? 1.f : 0.f) - mm);
    const size_t tidx = (size_t)p*NN*NN + (size_t)jx*NN + i;
    P[idx] = pv;  PT[tidx] = pv;
    T1[idx] = tv; T1T[tidx] = tv;
}

// ---------------------------------------------------------------------------
// Kernel F: D = A@B (+B)  (complex MFMA; optional D^T via LDS-staged
// coalesced transpose). unroll 8 widens the scheduler's load window.
// ---------------------------------------------------------------------------
template<bool ADD_B, bool WRITE_T>
__global__ __launch_bounds__(256) void mm_kernel(
    const unsigned short* __restrict__ A, const unsigned short* __restrict__ BT,
    unsigned short* __restrict__ D, unsigned short* __restrict__ DT)
{
    const int w    = threadIdx.x >> 6;
    const int lane = threadIdx.x & 63;
    const int m  = lane & 15;
    const int kg = lane >> 4;
    const int i0 = blockIdx.y*32;
    const int j0 = blockIdx.x*32;
    const int iw = (w>>1)*16;
    const int jw = (w&1)*16;

    __shared__ unsigned short sD[2][32][34];

    f32x4 RR = (f32x4)0.f, II = (f32x4)0.f, RI = (f32x4)0.f, IR = (f32x4)0.f;

#pragma unroll 8
    for (int c = 0; c < 16; ++c) {
        const int l0 = c*32 + kg*8;
        const bf16x8 ar = *reinterpret_cast<const bf16x8*>(A  + (size_t)(i0+iw+m)*NN + l0);
        const bf16x8 ai = *reinterpret_cast<const bf16x8*>(A  + (size_t)NN*NN + (size_t)(i0+iw+m)*NN + l0);
        const bf16x8 br = *reinterpret_cast<const bf16x8*>(BT + (size_t)(j0+jw+m)*NN + l0);
        const bf16x8 bi = *reinterpret_cast<const bf16x8*>(BT + (size_t)NN*NN + (size_t)(j0+jw+m)*NN + l0);
        RR = MFMA16(ar, br, RR, 0, 0, 0);
        II = MFMA16(ai, bi, II, 0, 0, 0);
        RI = MFMA16(ar, bi, RI, 0, 0, 0);
        IR = MFMA16(ai, br, IR, 0, 0, 0);
    }
    const int i = i0 + iw + kg*4;
    const int jx = j0 + jw + m;
    float adr[4] = {0.f,0.f,0.f,0.f}, adi[4] = {0.f,0.f,0.f,0.f};
    if (ADD_B) {
        const u16x4 badr = *reinterpret_cast<const u16x4*>(BT + (size_t)jx*NN + i);
        const u16x4 badi = *reinterpret_cast<const u16x4*>(BT + (size_t)NN*NN + (size_t)jx*NN + i);
#pragma unroll
        for (int r = 0; r < 4; ++r) { adr[r] = bf2f(badr[r]); adi[r] = bf2f(badi[r]); }
    }
#pragma unroll
    for (int r = 0; r < 4; ++r) {
        const unsigned short dr_ = f2bf(RR[r] - II[r] + adr[r]);
        const unsigned short di_ = f2bf(RI[r] + IR[r] + adi[r]);
        D[(size_t)(i+r)*NN + jx] = dr_;
        D[(size_t)NN*NN + (size_t)(i+r)*NN + jx] = di_;
        if (WRITE_T) {
            sD[0][iw + kg*4 + r][jw + m] = dr_;
            sD[1][iw + kg*4 + r][jw + m] = di_;
        }
    }
    if (WRITE_T) {
        __syncthreads();
        const int t = threadIdx.x;
        const int r8 = t >> 2, seg = t & 3;       // r8 0..63, seg 0..3
        const int plane = r8 >> 5, jloc = r8 & 31;
        u16x8 v;
#pragma unroll
        for (int e = 0; e < 8; ++e) v[e] = sD[plane][seg*8 + e][jloc];
        *reinterpret_cast<u16x8*>(DT + (size_t)plane*NN*NN +
                                  (size_t)(j0 + jloc)*NN + i0 + seg*8) = v;
    }
}

// ---------------------------------------------------------------------------
// Kernel G: X[k] = (S @ B[k]) * ic + params4[k]  (2 k's/block, sBT pitch 524)
// ---------------------------------------------------------------------------
__global__ __launch_bounds__(256) void final_kernel(
    const unsigned short* __restrict__ Sb, const unsigned short* __restrict__ Bb,
    const float* __restrict__ par4,
    const float* __restrict__ rhoX, const float* __restrict__ mu,
    float* __restrict__ Xout)
{
    const int k0 = blockIdx.x * 2;
    __shared__ __align__(16) unsigned short sBT[2][2][DD][524];

#pragma unroll
    for (int kk = 0; kk < 2; ++kk) {
        const unsigned short* Bk = Bb + (size_t)(k0 + kk)*2*NN*DD;
        for (int q = 0; q < 8; ++q) {
            const int t8 = q*256 + threadIdx.x;    // 0..2047
            const u16x8 v = *reinterpret_cast<const u16x8*>(Bk + (size_t)t8*8);
            const int flat = t8*8;
            const int p = flat >> 13, n = (flat >> 4) & 511, dd0 = flat & 15;
#pragma unroll
            for (int jj = 0; jj < 8; ++jj) sBT[kk][p][dd0+jj][n] = v[jj];
        }
    }
    __syncthreads();

    const int w    = threadIdx.x >> 6;
    const int lane = threadIdx.x & 63;
    const int m  = lane & 15;
    const int kg = lane >> 4;
    const int i0 = blockIdx.y*64 + w*16;

    f32x4 RR[2], II[2], RI[2], IR[2];
#pragma unroll
    for (int kk = 0; kk < 2; ++kk) {
        RR[kk] = (f32x4)0.f; II[kk] = (f32x4)0.f;
        RI[kk] = (f32x4)0.f; IR[kk] = (f32x4)0.f;
    }

#pragma unroll 4
    for (int c = 0; c < 16; ++c) {
        const int l0 = c*32 + kg*8;
        const bf16x8 ar = *reinterpret_cast<const bf16x8*>(Sb + (size_t)(i0+m)*NN + l0);
        const bf16x8 ai = *reinterpret_cast<const bf16x8*>(Sb + (size_t)NN*NN + (size_t)(i0+m)*NN + l0);
#pragma unroll
        for (int kk = 0; kk < 2; ++kk) {
            const bf16x8 br = *reinterpret_cast<const bf16x8*>(&sBT[kk][0][m][l0]);
            const bf16x8 bi = *reinterpret_cast<const bf16x8*>(&sBT[kk][1][m][l0]);
            RR[kk] = MFMA16(ar, br, RR[kk], 0, 0, 0);
            II[kk] = MFMA16(ai, bi, II[kk], 0, 0, 0);
            RI[kk] = MFMA16(ar, bi, RI[kk], 0, 0, 0);
            IR[kk] = MFMA16(ai, br, IR[kk], 0, 0, 0);
        }
    }
    const float ic = 1.f / (1.f/(2.f*rhoX[0]) + mu[0]);
#pragma unroll
    for (int kk = 0; kk < 2; ++kk) {
        const int k = k0 + kk;
#pragma unroll
        for (int r = 0; r < 4; ++r) {
            const int i = i0 + kg*4 + r;
            const int d = m;
            const size_t idx0 = ((size_t)(k*2+0)*NN + i)*DD + d;
            const size_t idx1 = ((size_t)(k*2+1)*NN + i)*DD + d;
            Xout[idx0] = (RR[kk][r] - II[kk][r])*ic + par4[idx0];
            Xout[idx1] = (RI[kk][r] + IR[kk][r])*ic + par4[idx1];
        }
    }
}

// ---------------------------------------------------------------------------
extern "C" void kernel_launch(void* const* d_in, const int* in_sizes, int n_in,
                              void* d_out, int out_size, void* d_ws, size_t ws_size,
                              hipStream_t stream) {
    const float* H     = (const float*)d_in[0];
    const float* U_RF  = (const float*)d_in[1];
    const float* U_BB  = (const float*)d_in[2];
    const float* W     = (const float*)d_in[3];
    const float* V_RF  = (const float*)d_in[4];
    const float* V_BB  = (const float*)d_in[5];
    const float* Y     = (const float*)d_in[6];
    // d_in[7] = rho (unused by reference)
    const float* rhoX  = (const float*)d_in[8];
    const float* mu    = (const float*)d_in[9];
    const float* par4  = (const float*)d_in[10];
    float* Xout = (float*)d_out;

    unsigned short* u = (unsigned short*)d_ws;
    const size_t bigE = (size_t)KK*2*NN*DD;    // 8,388,608
    const size_t plE  = (size_t)2*NN*NN;       //   524,288
    unsigned short* tempb = u;
    unsigned short* TWb   = tempb + bigE;
    unsigned short* Bb    = TWb + bigE;
    unsigned int*   GT2f  = (unsigned int*)(Bb + bigE);          // 512*6144 dwords
    unsigned short* VRFb  = (unsigned short*)(GT2f + (size_t)KK*6144);  // 512*128
    unsigned short* Pm    = VRFb + (size_t)NN*128;
    unsigned short* PmT   = Pm  + plE;
    unsigned short* T1    = PmT + plE;
    unsigned short* T1T   = T1  + plE;
    unsigned short* Q     = T1T + plE;
    unsigned short* QT    = Q   + plE;
    unsigned short* R     = QT  + plE;
    unsigned short* T2    = R   + plE;
    unsigned short* T2T   = T2  + plE;
    unsigned short* Ss    = T2T + plE;
    float* Epart = (float*)(Ss + plE);                           // 8*plE floats

    small_kernel<<<KK, 256, 0, stream>>>(U_RF, U_BB, W, V_BB, V_RF, GT2f, VRFb);
    prep_main<<<KK*4, 512, 0, stream>>>(H, GT2f, VRFb, Y, rhoX,
                                        tempb, TWb, Bb);
    egemm_kernel<<<dim3(64, 8), 256, 0, stream>>>(TWb, tempb, Epart);
    reduceinit_kernel<<<(int)(plE/256), 256, 0, stream>>>(Epart, rhoX, mu,
                                                          Pm, PmT, T1, T1T);
    // S = (I+P)(I+P^2)(I+P^4), P = -M  -> Neumann degree 7 (trunc ~1.1e-3;
    // bf16 noise ~1e-3; threshold 2.6e-3). 4 matmuls (was 6 for degree 15).
    mm_kernel<false,true ><<<dim3(16,16), 256, 0, stream>>>(Pm, PmT, Q,  QT);   // Q  = P*P
    mm_kernel<true ,true ><<<dim3(16,16), 256, 0, stream>>>(Q,  T1T, T2, T2T);  // T2 = T1 + Q*T1  (deg 3)
    mm_kernel<false,false><<<dim3(16,16), 256, 0, stream>>>(Q,  QT,  R,  nullptr); // R = Q*Q
    mm_kernel<true ,false><<<dim3(16,16), 256, 0, stream>>>(R,  T2T, Ss, nullptr); // S = T2 + R*T2 (deg 7)
    final_kernel<<<dim3(KK/2, 8), 256, 0, stream>>>(Ss, Bb, par4, rhoX, mu, Xout);
}

// Round 18
// 192.103 us; speedup vs baseline: 1.2527x; 1.0052x over previous
//
#include <hip/hip_runtime.h>

#define KK 512
#define NN 512
#define DD 16
#define MM 64
#define MRF 16
#define NRF 64

typedef __attribute__((ext_vector_type(8))) short bf16x8;
typedef __attribute__((ext_vector_type(4))) float f32x4;
typedef __attribute__((ext_vector_type(8))) unsigned short u16x8;
typedef __attribute__((ext_vector_type(4))) unsigned short u16x4;

#define MFMA16 __builtin_amdgcn_mfma_f32_16x16x32_bf16

static __device__ __forceinline__ unsigned short f2bf(float x) {
    unsigned int u = __float_as_uint(x);
    u += 0x7fffu + ((u >> 16) & 1u);
    return (unsigned short)(u >> 16);
}
static __device__ __forceinline__ float bf2f(unsigned short b) {
    return __uint_as_float((unsigned int)b << 16);
}
static __device__ __forceinline__ unsigned int pk2(float lo, float hi) {
    return (unsigned int)f2bf(lo) | ((unsigned int)f2bf(hi) << 16);
}

union frag_cast { uint4 u; bf16x8 v; };

// ---------------------------------------------------------------------------
// Kernel B: per-k G = U_RF@U_BB, GW = G@W; emit WAVE-COALESCED fragment buffer
//   GT2f[k][ks 0..3][s 0..5][lane 0..63][j 0..3]  (6144 dwords/k)
// Folds vrfb: block k converts V_RF column k -> VRFb[k][vr(64)|vi(64)] bf16.
// ---------------------------------------------------------------------------
__global__ __launch_bounds__(256) void small_kernel(
    const float* __restrict__ U_RF, const float* __restrict__ U_BB,
    const float* __restrict__ W, const float* __restrict__ V_BB,
    const float* __restrict__ V_RF,
    unsigned int* __restrict__ GT2f, unsigned short* __restrict__ VRFb)
{
    const int k = blockIdx.x, t = threadIdx.x;
    __shared__ float sUR[2][MM][17];
    __shared__ float sUB[2][MRF][DD], sW[2][DD][DD];
    __shared__ float sVB[2][NRF][17];
    __shared__ float sG[2][MM][17], sGW[2][MM][17];

    if (t < 128) {
        const int p = t >> 6, r = t & 63;
        VRFb[(size_t)k*128 + t] = f2bf(V_RF[((size_t)p*NN + k)*NRF + r]);
    }

    const float* uf = U_RF + (size_t)k*2*MM*MRF;
    for (int i = t; i < 2*MM*MRF; i += 256) sUR[i>>10][(i>>4)&63][i&15] = uf[i];
    const float* ub = U_BB + (size_t)k*2*MRF*DD;
    for (int i = t; i < 2*MRF*DD; i += 256) sUB[i>>8][(i>>4)&15][i&15] = ub[i];
    const float* ww = W + (size_t)k*2*DD*DD;
    for (int i = t; i < 2*DD*DD; i += 256) sW[i>>8][(i>>4)&15][i&15] = ww[i];
    const float* vb = V_BB + (size_t)k*2*NRF*DD;
    for (int i = t; i < 2*NRF*DD; i += 256) sVB[i>>10][(i>>4)&63][i&15] = vb[i];
    __syncthreads();

    // Phase 1: G[m][d]  (thread = (m, d-quad))
    {
        const int m = t >> 2, dq = (t & 3) * 4;
        float gr[4] = {0,0,0,0}, gi[4] = {0,0,0,0};
#pragma unroll
        for (int r = 0; r < MRF; ++r) {
            const float ur = sUR[0][m][r], ui = sUR[1][m][r];
#pragma unroll
            for (int q = 0; q < 4; ++q) {
                const float br = sUB[0][r][dq+q], bi = sUB[1][r][dq+q];
                gr[q] += ur*br - ui*bi;
                gi[q] += ur*bi + ui*br;
            }
        }
#pragma unroll
        for (int q = 0; q < 4; ++q) { sG[0][m][dq+q] = gr[q]; sG[1][m][dq+q] = gi[q]; }
    }
    __syncthreads();

    // Phase 2: GW = G @ W
    {
        const int m = t >> 2, dq = (t & 3) * 4;
        float gwr[4] = {0,0,0,0}, gwi[4] = {0,0,0,0};
#pragma unroll
        for (int dp = 0; dp < DD; ++dp) {
            const float gr = sG[0][m][dp], gi = sG[1][m][dp];
#pragma unroll
            for (int q = 0; q < 4; ++q) {
                const float wr = sW[0][dp][dq+q], wi = sW[1][dp][dq+q];
                gwr[q] += gr*wr - gi*wi;
                gwi[q] += gr*wi + gi*wr;
            }
        }
#pragma unroll
        for (int q = 0; q < 4; ++q) { sGW[0][m][dq+q] = gwr[q]; sGW[1][m][dq+q] = gwi[q]; }
    }
    __syncthreads();

    // Phase 3: pack GT2f (thread -> lane64 = t&63, ks = t>>6)
    {
        const int lane64 = t & 63, ks = t >> 6;
        const int c = lane64 & 15, kg = lane64 >> 4;
        const int e2b = ks*16 + kg*4;
        unsigned int* dstk = GT2f + (size_t)k*6144 + ks*1536 + lane64*4;
#pragma unroll
        for (int s = 0; s < 6; ++s) {
            uint4 o;
#pragma unroll
            for (int j = 0; j < 4; ++j) {
                const int e2 = e2b + j;
                const int sl0 = 2*e2;
                const int m0 = sl0 & 63, hi = sl0 >> 6;
                const int m1 = m0 + 1;
                float v0, v1;
                if (s == 0)      { v0 = hi ? sG[1][m0][c]   : sG[0][m0][c];
                                   v1 = hi ? sG[1][m1][c]   : sG[0][m1][c]; }
                else if (s == 1) { v0 = hi ? -sG[0][m0][c]  : sG[1][m0][c];
                                   v1 = hi ? -sG[0][m1][c]  : sG[1][m1][c]; }
                else if (s == 2) { v0 = hi ? sGW[1][m0][c]  : sGW[0][m0][c];
                                   v1 = hi ? sGW[1][m1][c]  : sGW[0][m1][c]; }
                else if (s == 3) { v0 = hi ? -sGW[0][m0][c] : sGW[1][m0][c];
                                   v1 = hi ? -sGW[0][m1][c] : sGW[1][m1][c]; }
                else if (s == 4) { v0 = hi ? -sVB[1][m0][c] : sVB[0][m0][c];
                                   v1 = hi ? -sVB[1][m1][c] : sVB[0][m1][c]; }
                else             { v0 = hi ? sVB[0][m0][c]  : sVB[1][m0][c];
                                   v1 = hi ? sVB[0][m1][c]  : sVB[1][m1][c]; }
                ((unsigned int*)&o)[j] = pk2(v0, v1);
            }
            *reinterpret_cast<uint4*>(dstk + s*256) = o;
        }
    }
}

// ---------------------------------------------------------------------------
// Kernel C: prep_main (r14 config, at structural floor ~78us — unchanged).
// ---------------------------------------------------------------------------
__global__ __launch_bounds__(512, 8) void prep_main(
    const float* __restrict__ H, const unsigned int* __restrict__ GT2f,
    const unsigned short* __restrict__ VRFb,
    const float* __restrict__ Y, const float* __restrict__ rhoX,
    unsigned short* __restrict__ tempb, unsigned short* __restrict__ TWb,
    unsigned short* __restrict__ Bb)
{
    const int nb = blockIdx.x & 3;
    const int k  = blockIdx.x >> 2;
    const int t  = threadIdx.x;
    const int n0 = nb*128;

    __shared__ unsigned int sH[64][132];   // 33.8 KB  [e2][ncol]

    const float* Hk = H + (size_t)k*128*NN + n0;
#pragma unroll
    for (int pass = 0; pass < 4; ++pass) {
        const int e2 = pass*16 + (t >> 5);
        const int c4 = (t & 31) * 4;
        const float4 a = *reinterpret_cast<const float4*>(Hk + (size_t)(2*e2  )*NN + c4);
        const float4 b = *reinterpret_cast<const float4*>(Hk + (size_t)(2*e2+1)*NN + c4);
        uint4 d;
        d.x = pk2(a.x, b.x); d.y = pk2(a.y, b.y);
        d.z = pk2(a.z, b.z); d.w = pk2(a.w, b.w);
        *reinterpret_cast<uint4*>(&sH[e2][c4]) = d;
    }

    const int w = t >> 6, lane = t & 63;
    const int c = lane & 15, kg = lane >> 4;
    const float irx = 1.f / rhoX[0];
    const int ncol = w*16 + c;
    const int n = n0 + ncol;

    const size_t o0 = ((size_t)(k*2 + 0)*NN + n)*DD + kg*4;
    const size_t o1 = ((size_t)(k*2 + 1)*NN + n)*DD + kg*4;
    const float4 y0 = *reinterpret_cast<const float4*>(Y + o0);
    const float4 y1 = *reinterpret_cast<const float4*>(Y + o1);

    __syncthreads();

    f32x4 aTr = (f32x4)0.f, aTi = (f32x4)0.f;
    f32x4 aWr = (f32x4)0.f, aWi = (f32x4)0.f;
    f32x4 aVr = (f32x4)0.f, aVi = (f32x4)0.f;

    const unsigned int* gk = GT2f + (size_t)k*6144 + lane*4;

#pragma unroll
    for (int ks = 0; ks < 4; ++ks) {
        const int slot0 = ks*32 + kg*8;
        const int e2b = ks*16 + kg*4;
        frag_cast fh, g0, g1, g2, g3, v0, v1;
        fh.u.x = sH[e2b+0][ncol];
        fh.u.y = sH[e2b+1][ncol];
        fh.u.z = sH[e2b+2][ncol];
        fh.u.w = sH[e2b+3][ncol];
        const unsigned int* gb = gk + ks*1536;
        g0.u = *reinterpret_cast<const uint4*>(gb);
        g1.u = *reinterpret_cast<const uint4*>(gb + 256);
        g2.u = *reinterpret_cast<const uint4*>(gb + 512);
        g3.u = *reinterpret_cast<const uint4*>(gb + 768);
        v0.u = *reinterpret_cast<const uint4*>(gb + 1024);
        v1.u = *reinterpret_cast<const uint4*>(gb + 1280);
        const bf16x8 bv = *reinterpret_cast<const bf16x8*>(VRFb + (size_t)n*128 + slot0);

        aTr = MFMA16(g0.v, fh.v, aTr, 0, 0, 0);
        aTi = MFMA16(g1.v, fh.v, aTi, 0, 0, 0);
        aWr = MFMA16(g2.v, fh.v, aWr, 0, 0, 0);
        aWi = MFMA16(g3.v, fh.v, aWi, 0, 0, 0);
        aVr = MFMA16(v0.v, bv, aVr, 0, 0, 0);
        aVi = MFMA16(v1.v, bv, aVi, 0, 0, 0);
    }

    {
        const float y0a[4] = {y0.x, y0.y, y0.z, y0.w};
        const float y1a[4] = {y1.x, y1.y, y1.z, y1.w};
        u16x4 tr_, ti_, wr_, wi_, br_, bi_;
#pragma unroll
        for (int r = 0; r < 4; ++r) {
            tr_[r] = f2bf(aTr[r]);  ti_[r] = f2bf(aTi[r]);
            wr_[r] = f2bf(aWr[r]);  wi_[r] = f2bf(aWi[r]);
            br_[r] = f2bf(aWr[r] + 0.5f*(aVr[r]*irx - y0a[r]));
            bi_[r] = f2bf(aWi[r] + 0.5f*(aVi[r]*irx - y1a[r]));
        }
        *reinterpret_cast<u16x4*>(tempb + o0) = tr_;
        *reinterpret_cast<u16x4*>(tempb + o1) = ti_;
        *reinterpret_cast<u16x4*>(TWb + o0)   = wr_;
        *reinterpret_cast<u16x4*>(TWb + o1)   = wi_;
        *reinterpret_cast<u16x4*>(Bb + o0)    = br_;
        *reinterpret_cast<u16x4*>(Bb + o1)    = bi_;
    }
}

// ---------------------------------------------------------------------------
// Kernel D: Epart[ks] = sum_{kappa slice} TW @ temp^H  (split-8)
// ---------------------------------------------------------------------------
__global__ __launch_bounds__(256) void egemm_kernel(
    const unsigned short* __restrict__ TWb, const unsigned short* __restrict__ tmpb,
    float* __restrict__ Epart)
{
    const int ib = blockIdx.x >> 3;
    const int ks = blockIdx.x & 7;
    const int jb = blockIdx.y;
    const int w    = threadIdx.x >> 6;
    const int lane = threadIdx.x & 63;
    const int m  = lane & 15;
    const int kg = lane >> 4;
    const int iw = ib*64 + (w>>1)*32;
    const int jw = jb*64 + (w&1)*32;
    const int d0  = (kg & 1) * 8;
    const int kof = kg >> 1;

    f32x4 RR[2][2], II[2][2], RI[2][2], IR[2][2];
#pragma unroll
    for (int is = 0; is < 2; ++is)
#pragma unroll
        for (int js = 0; js < 2; ++js) {
            RR[is][js] = (f32x4)0.f; II[is][js] = (f32x4)0.f;
            RI[is][js] = (f32x4)0.f; IR[is][js] = (f32x4)0.f;
        }

#pragma unroll 4
    for (int c = 0; c < 32; ++c) {
        const int chunk = ks*32 + c;
        const int kp = chunk*2 + kof;
        const unsigned short* Ab = TWb  + ((size_t)(kp*2+0)*NN + iw + m)*DD + d0;
        const unsigned short* Bb2 = tmpb + ((size_t)(kp*2+0)*NN + jw + m)*DD + d0;
        bf16x8 ar[2], ai[2], br[2], bi[2];
#pragma unroll
        for (int is = 0; is < 2; ++is) {
            ar[is] = *reinterpret_cast<const bf16x8*>(Ab + (size_t)is*16*DD);
            ai[is] = *reinterpret_cast<const bf16x8*>(Ab + (size_t)NN*DD + (size_t)is*16*DD);
        }
#pragma unroll
        for (int js = 0; js < 2; ++js) {
            br[js] = *reinterpret_cast<const bf16x8*>(Bb2 + (size_t)js*16*DD);
            bi[js] = *reinterpret_cast<const bf16x8*>(Bb2 + (size_t)NN*DD + (size_t)js*16*DD);
        }
#pragma unroll
        for (int is = 0; is < 2; ++is)
#pragma unroll
            for (int js = 0; js < 2; ++js) {
                RR[is][js] = MFMA16(ar[is], br[js], RR[is][js], 0, 0, 0);
                II[is][js] = MFMA16(ai[is], bi[js], II[is][js], 0, 0, 0);
                RI[is][js] = MFMA16(ar[is], bi[js], RI[is][js], 0, 0, 0);
                IR[is][js] = MFMA16(ai[is], br[js], IR[is][js], 0, 0, 0);
            }
    }

    float* Eb = Epart + (size_t)ks*2*NN*NN;
#pragma unroll
    for (int is = 0; is < 2; ++is)
#pragma unroll
        for (int js = 0; js < 2; ++js) {
            const int i = iw + is*16 + kg*4;
            const int jx = jw + js*16 + m;
#pragma unroll
            for (int r = 0; r < 4; ++r) {
                Eb[(size_t)(i+r)*NN + jx]               = RR[is][js][r] + II[is][js][r];
                Eb[(size_t)NN*NN + (size_t)(i+r)*NN + jx] = IR[is][js][r] - RI[is][js][r];
            }
        }
}

// ---------------------------------------------------------------------------
// Kernel E: M = (sum of 8 Epart)/c ; P = -M ; T1 = I + P  (bf16 + transposes)
// ---------------------------------------------------------------------------
__global__ __launch_bounds__(256) void reduceinit_kernel(
    const float* __restrict__ Epart,
    const float* __restrict__ rhoX, const float* __restrict__ mu,
    unsigned short* __restrict__ P, unsigned short* __restrict__ PT,
    unsigned short* __restrict__ T1, unsigned short* __restrict__ T1T)
{
    const size_t idx = (size_t)blockIdx.x*256 + threadIdx.x;   // over 2*NN*NN
    const float ic = 1.f / (1.f/(2.f*rhoX[0]) + mu[0]);
    const size_t pl = (size_t)2*NN*NN;
    float s = 0.f;
#pragma unroll
    for (int ks = 0; ks < 8; ++ks) s += Epart[(size_t)ks*pl + idx];
    const float mm = s * ic;
    const int p = (int)(idx / ((size_t)NN*NN));
    const size_t rem = idx - (size_t)p*NN*NN;
    const int i = (int)(rem / NN), jx = (int)(rem % NN);
    const unsigned short pv = f2bf(-mm);
    const unsigned short tv = f2bf(((p == 0 && i == jx) ? 1.f : 0.f) - mm);
    const size_t tidx = (size_t)p*NN*NN + (size_t)jx*NN + i;
    P[idx] = pv;  PT[tidx] = pv;
    T1[idx] = tv; T1T[tidx] = tv;
}

// ---------------------------------------------------------------------------
// mm body (device): D = A@B (+B), optional D^T via LDS-staged transpose.
// ---------------------------------------------------------------------------
template<bool ADD_B, bool WRITE_T>
static __device__ __forceinline__ void mm_body(
    const unsigned short* __restrict__ A, const unsigned short* __restrict__ BT,
    unsigned short* __restrict__ D, unsigned short* __restrict__ DT,
    unsigned short (*sD)[32][34])
{
    const int w    = threadIdx.x >> 6;
    const int lane = threadIdx.x & 63;
    const int m  = lane & 15;
    const int kg = lane >> 4;
    const int i0 = blockIdx.y*32;
    const int j0 = blockIdx.x*32;
    const int iw = (w>>1)*16;
    const int jw = (w&1)*16;

    f32x4 RR = (f32x4)0.f, II = (f32x4)0.f, RI = (f32x4)0.f, IR = (f32x4)0.f;

#pragma unroll 8
    for (int c = 0; c < 16; ++c) {
        const int l0 = c*32 + kg*8;
        const bf16x8 ar = *reinterpret_cast<const bf16x8*>(A  + (size_t)(i0+iw+m)*NN + l0);
        const bf16x8 ai = *reinterpret_cast<const bf16x8*>(A  + (size_t)NN*NN + (size_t)(i0+iw+m)*NN + l0);
        const bf16x8 br = *reinterpret_cast<const bf16x8*>(BT + (size_t)(j0+jw+m)*NN + l0);
        const bf16x8 bi = *reinterpret_cast<const bf16x8*>(BT + (size_t)NN*NN + (size_t)(j0+jw+m)*NN + l0);
        RR = MFMA16(ar, br, RR, 0, 0, 0);
        II = MFMA16(ai, bi, II, 0, 0, 0);
        RI = MFMA16(ar, bi, RI, 0, 0, 0);
        IR = MFMA16(ai, br, IR, 0, 0, 0);
    }
    const int i = i0 + iw + kg*4;
    const int jx = j0 + jw + m;
    float adr[4] = {0.f,0.f,0.f,0.f}, adi[4] = {0.f,0.f,0.f,0.f};
    if (ADD_B) {
        const u16x4 badr = *reinterpret_cast<const u16x4*>(BT + (size_t)jx*NN + i);
        const u16x4 badi = *reinterpret_cast<const u16x4*>(BT + (size_t)NN*NN + (size_t)jx*NN + i);
#pragma unroll
        for (int r = 0; r < 4; ++r) { adr[r] = bf2f(badr[r]); adi[r] = bf2f(badi[r]); }
    }
#pragma unroll
    for (int r = 0; r < 4; ++r) {
        const unsigned short dr_ = f2bf(RR[r] - II[r] + adr[r]);
        const unsigned short di_ = f2bf(RI[r] + IR[r] + adi[r]);
        D[(size_t)(i+r)*NN + jx] = dr_;
        D[(size_t)NN*NN + (size_t)(i+r)*NN + jx] = di_;
        if (WRITE_T) {
            sD[0][iw + kg*4 + r][jw + m] = dr_;
            sD[1][iw + kg*4 + r][jw + m] = di_;
        }
    }
    if (WRITE_T) {
        __syncthreads();
        const int t = threadIdx.x;
        const int r8 = t >> 2, seg = t & 3;       // r8 0..63, seg 0..3
        const int plane = r8 >> 5, jloc = r8 & 31;
        u16x8 v;
#pragma unroll
        for (int e = 0; e < 8; ++e) v[e] = sD[plane][seg*8 + e][jloc];
        *reinterpret_cast<u16x8*>(DT + (size_t)plane*NN*NN +
                                  (size_t)(j0 + jloc)*NN + i0 + seg*8) = v;
    }
}

template<bool ADD_B, bool WRITE_T>
__global__ __launch_bounds__(256) void mm_kernel(
    const unsigned short* __restrict__ A, const unsigned short* __restrict__ BT,
    unsigned short* __restrict__ D, unsigned short* __restrict__ DT)
{
    __shared__ unsigned short sD[2][32][34];
    mm_body<ADD_B, WRITE_T>(A, BT, D, DT, sD);
}

// Fused pair: z==0 -> T2 = T1 + Q@T1 (writes T2, T2T); z==1 -> R = Q@Q.
// The two products are independent (both read only Q/T1) -> one launch.
__global__ __launch_bounds__(256) void mm_pair_kernel(
    const unsigned short* __restrict__ Q, const unsigned short* __restrict__ QT,
    const unsigned short* __restrict__ T1T,
    unsigned short* __restrict__ T2, unsigned short* __restrict__ T2T,
    unsigned short* __restrict__ R)
{
    __shared__ unsigned short sD[2][32][34];
    if (blockIdx.z == 0) {
        mm_body<true, true>(Q, T1T, T2, T2T, sD);
    } else {
        mm_body<false, false>(Q, QT, R, nullptr, sD);
    }
}

// ---------------------------------------------------------------------------
// Kernel G: X[k] = (S @ B[k]) * ic + params4[k]  (2 k's/block, sBT pitch 524)
// ---------------------------------------------------------------------------
__global__ __launch_bounds__(256) void final_kernel(
    const unsigned short* __restrict__ Sb, const unsigned short* __restrict__ Bb,
    const float* __restrict__ par4,
    const float* __restrict__ rhoX, const float* __restrict__ mu,
    float* __restrict__ Xout)
{
    const int k0 = blockIdx.x * 2;
    __shared__ __align__(16) unsigned short sBT[2][2][DD][524];

#pragma unroll
    for (int kk = 0; kk < 2; ++kk) {
        const unsigned short* Bk = Bb + (size_t)(k0 + kk)*2*NN*DD;
        for (int q = 0; q < 8; ++q) {
            const int t8 = q*256 + threadIdx.x;    // 0..2047
            const u16x8 v = *reinterpret_cast<const u16x8*>(Bk + (size_t)t8*8);
            const int flat = t8*8;
            const int p = flat >> 13, n = (flat >> 4) & 511, dd0 = flat & 15;
#pragma unroll
            for (int jj = 0; jj < 8; ++jj) sBT[kk][p][dd0+jj][n] = v[jj];
        }
    }
    __syncthreads();

    const int w    = threadIdx.x >> 6;
    const int lane = threadIdx.x & 63;
    const int m  = lane & 15;
    const int kg = lane >> 4;
    const int i0 = blockIdx.y*64 + w*16;

    f32x4 RR[2], II[2], RI[2], IR[2];
#pragma unroll
    for (int kk = 0; kk < 2; ++kk) {
        RR[kk] = (f32x4)0.f; II[kk] = (f32x4)0.f;
        RI[kk] = (f32x4)0.f; IR[kk] = (f32x4)0.f;
    }

#pragma unroll 4
    for (int c = 0; c < 16; ++c) {
        const int l0 = c*32 + kg*8;
        const bf16x8 ar = *reinterpret_cast<const bf16x8*>(Sb + (size_t)(i0+m)*NN + l0);
        const bf16x8 ai = *reinterpret_cast<const bf16x8*>(Sb + (size_t)NN*NN + (size_t)(i0+m)*NN + l0);
#pragma unroll
        for (int kk = 0; kk < 2; ++kk) {
            const bf16x8 br = *reinterpret_cast<const bf16x8*>(&sBT[kk][0][m][l0]);
            const bf16x8 bi = *reinterpret_cast<const bf16x8*>(&sBT[kk][1][m][l0]);
            RR[kk] = MFMA16(ar, br, RR[kk], 0, 0, 0);
            II[kk] = MFMA16(ai, bi, II[kk], 0, 0, 0);
            RI[kk] = MFMA16(ar, bi, RI[kk], 0, 0, 0);
            IR[kk] = MFMA16(ai, br, IR[kk], 0, 0, 0);
        }
    }
    const float ic = 1.f / (1.f/(2.f*rhoX[0]) + mu[0]);
#pragma unroll
    for (int kk = 0; kk < 2; ++kk) {
        const int k = k0 + kk;
#pragma unroll
        for (int r = 0; r < 4; ++r) {
            const int i = i0 + kg*4 + r;
            const int d = m;
            const size_t idx0 = ((size_t)(k*2+0)*NN + i)*DD + d;
            const size_t idx1 = ((size_t)(k*2+1)*NN + i)*DD + d;
            Xout[idx0] = (RR[kk][r] - II[kk][r])*ic + par4[idx0];
            Xout[idx1] = (RI[kk][r] + IR[kk][r])*ic + par4[idx1];
        }
    }
}

// ---------------------------------------------------------------------------
extern "C" void kernel_launch(void* const* d_in, const int* in_sizes, int n_in,
                              void* d_out, int out_size, void* d_ws, size_t ws_size,
                              hipStream_t stream) {
    const float* H     = (const float*)d_in[0];
    const float* U_RF  = (const float*)d_in[1];
    const float* U_BB  = (const float*)d_in[2];
    const float* W     = (const float*)d_in[3];
    const float* V_RF  = (const float*)d_in[4];
    const float* V_BB  = (const float*)d_in[5];
    const float* Y     = (const float*)d_in[6];
    // d_in[7] = rho (unused by reference)
    const float* rhoX  = (const float*)d_in[8];
    const float* mu    = (const float*)d_in[9];
    const float* par4  = (const float*)d_in[10];
    float* Xout = (float*)d_out;

    unsigned short* u = (unsigned short*)d_ws;
    const size_t bigE = (size_t)KK*2*NN*DD;    // 8,388,608
    const size_t plE  = (size_t)2*NN*NN;       //   524,288
    unsigned short* tempb = u;
    unsigned short* TWb   = tempb + bigE;
    unsigned short* Bb    = TWb + bigE;
    unsigned int*   GT2f  = (unsigned int*)(Bb + bigE);          // 512*6144 dwords
    unsigned short* VRFb  = (unsigned short*)(GT2f + (size_t)KK*6144);  // 512*128
    unsigned short* Pm    = VRFb + (size_t)NN*128;
    unsigned short* PmT   = Pm  + plE;
    unsigned short* T1    = PmT + plE;
    unsigned short* T1T   = T1  + plE;
    unsigned short* Q     = T1T + plE;
    unsigned short* QT    = Q   + plE;
    unsigned short* R     = QT  + plE;
    unsigned short* T2    = R   + plE;
    unsigned short* T2T   = T2  + plE;
    unsigned short* Ss    = T2T + plE;
    float* Epart = (float*)(Ss + plE);                           // 8*plE floats

    small_kernel<<<KK, 256, 0, stream>>>(U_RF, U_BB, W, V_BB, V_RF, GT2f, VRFb);
    prep_main<<<KK*4, 512, 0, stream>>>(H, GT2f, VRFb, Y, rhoX,
                                        tempb, TWb, Bb);
    egemm_kernel<<<dim3(64, 8), 256, 0, stream>>>(TWb, tempb, Epart);
    reduceinit_kernel<<<(int)(plE/256), 256, 0, stream>>>(Epart, rhoX, mu,
                                                          Pm, PmT, T1, T1T);
    // S = (I+P)(I+P^2)(I+P^4), degree 7.  3 launches:
    //   Q = P*P ;  {T2 = T1 + Q*T1 || R = Q*Q} fused ;  S = T2 + R*T2
    mm_kernel<false,true ><<<dim3(16,16), 256, 0, stream>>>(Pm, PmT, Q, QT);
    mm_pair_kernel<<<dim3(16,16,2), 256, 0, stream>>>(Q, QT, T1T, T2, T2T, R);
    mm_kernel<true ,false><<<dim3(16,16), 256, 0, stream>>>(R, T2T, Ss, nullptr);
    final_kernel<<<dim3(KK/2, 8), 256, 0, stream>>>(Ss, Bb, par4, rhoX, mu, Xout);
}